// Round 8
// baseline (719.529 us; speedup 1.0000x reference)
//
#include <hip/hip_runtime.h>
#include <hip/hip_bf16.h>
#include <math.h>

#define BB 64
#define LL 384
#define DD 128
#define HH 8
#define DHH 16
#define DEPTH 6
#define FFD 512
#define MROWS (BB*LL)      // 24576
#define COUT 128
#define KP (LL*DD)         // 49152

typedef short bf16x8 __attribute__((ext_vector_type(8)));
typedef float f32x4 __attribute__((ext_vector_type(4)));

__device__ __forceinline__ unsigned short f2bs(float x) {
    __hip_bfloat16 h = __float2bfloat16(x);
    return *reinterpret_cast<unsigned short*>(&h);
}
__device__ __forceinline__ float bs2f(unsigned short u) {
    unsigned int v = ((unsigned int)u) << 16;
    return __uint_as_float(v);
}

// ---------------- embed + axial pos ----------------
__global__ __launch_bounds__(256) void embed_kernel(
    const int* __restrict__ x_enc, const float* __restrict__ emb,
    const float* __restrict__ pos1, const float* __restrict__ pos2,
    float* __restrict__ x1, float* __restrict__ x2)
{
    int t = blockIdx.x * 256 + threadIdx.x;      // over MROWS * 32 float4
    int row = t >> 5;
    int c4 = t & 31;
    int l = row % LL;
    int tok = x_enc[row];
    float4 a = ((const float4*)(emb + (size_t)tok * DD))[c4];
    float4 b = ((const float4*)(pos1 + (l / 25) * DD))[c4];
    float4 c = ((const float4*)(pos2 + (l % 25) * DD))[c4];
    float4 r = make_float4(a.x + b.x + c.x, a.y + b.y + c.y,
                           a.z + b.z + c.z, a.w + b.w + c.w);
    ((float4*)x1)[t] = r;
    ((float4*)x2)[t] = r;
}

// ---------------- weight cast + transpose: W[K,N] fp32 -> Wt[N,K] bf16 ----------------
__global__ __launch_bounds__(256) void castT_kernel(
    const float* __restrict__ src, __hip_bfloat16* __restrict__ dst, int K, int N,
    long sstride, long dstride)
{
    __shared__ float tile[32][33];
    int kb = blockIdx.x * 32, nb = blockIdx.y * 32;
    int tx = threadIdx.x & 31, ty = threadIdx.x >> 5;   // ty 0..7
    const float* s = src + (size_t)blockIdx.z * sstride;
    __hip_bfloat16* d = dst + (size_t)blockIdx.z * dstride;
    #pragma unroll
    for (int r = 0; r < 32; r += 8)
        tile[r + ty][tx] = s[(size_t)(kb + r + ty) * N + nb + tx];
    __syncthreads();
    #pragma unroll
    for (int r = 0; r < 32; r += 8)
        d[(size_t)(nb + r + ty) * K + kb + tx] = __float2bfloat16(tile[tx][r + ty]);
}

// ---------------- LayerNorm (wave per row) -> bf16 out (layer-0 ln1 only) ----------------
__global__ __launch_bounds__(256) void ln_kernel(
    const float* __restrict__ x, const float* __restrict__ g,
    const float* __restrict__ b, __hip_bfloat16* __restrict__ y)
{
    int wave = threadIdx.x >> 6;
    int lane = threadIdx.x & 63;
    int row = blockIdx.x * 4 + wave;
    float2 v = ((const float2*)(x + (size_t)row * DD))[lane];
    float2 gg = ((const float2*)g)[lane];
    float2 bb = ((const float2*)b)[lane];
    float s = v.x + v.y;
    float sq = v.x * v.x + v.y * v.y;
    #pragma unroll
    for (int off = 32; off > 0; off >>= 1) {
        s += __shfl_down(s, off, 64);
        sq += __shfl_down(sq, off, 64);
    }
    s = __shfl(s, 0, 64);
    sq = __shfl(sq, 0, 64);
    float mean = s * (1.0f / DD);
    float var = sq * (1.0f / DD) - mean * mean;
    float rstd = rsqrtf(var + 1e-5f);
    __hip_bfloat16* yp = y + (size_t)row * DD + lane * 2;
    yp[0] = __float2bfloat16((v.x - mean) * rstd * gg.x + bb.x);
    yp[1] = __float2bfloat16((v.y - mean) * rstd * gg.y + bb.y);
}

// avg + LN -> fp32 out (for final projection)
__global__ __launch_bounds__(256) void avgln_kernel(
    const float* __restrict__ xa, const float* __restrict__ xb,
    const float* __restrict__ g, const float* __restrict__ b, float* __restrict__ y)
{
    int wave = threadIdx.x >> 6;
    int lane = threadIdx.x & 63;
    int row = blockIdx.x * 4 + wave;
    float2 va = ((const float2*)(xa + (size_t)row * DD))[lane];
    float2 vb = ((const float2*)(xb + (size_t)row * DD))[lane];
    float2 v = make_float2((va.x + vb.x) * 0.5f, (va.y + vb.y) * 0.5f);
    float2 gg = ((const float2*)g)[lane];
    float2 bb = ((const float2*)b)[lane];
    float s = v.x + v.y;
    float sq = v.x * v.x + v.y * v.y;
    #pragma unroll
    for (int off = 32; off > 0; off >>= 1) {
        s += __shfl_down(s, off, 64);
        sq += __shfl_down(sq, off, 64);
    }
    s = __shfl(s, 0, 64);
    sq = __shfl(sq, 0, 64);
    float mean = s * (1.0f / DD);
    float var = sq * (1.0f / DD) - mean * mean;
    float rstd = rsqrtf(var + 1e-5f);
    float2 o;
    o.x = (v.x - mean) * rstd * gg.x + bb.x;
    o.y = (v.y - mean) * rstd * gg.y + bb.y;
    ((float2*)(y + (size_t)row * DD))[lane] = o;
}

// ---------------- bf16 MFMA GEMM (optional fused row-LayerNorm epilogue) ----------------
// A[M,K] bf16 row-major, Bt[N,K] bf16 row-major. BM=64, BN=128, K-tile=128.
// LNOUT requires N==128 and gridDim.x==1 (block holds complete output rows):
// epilogue stages the 64x128 fp32 tile in LDS (reusing Bs), writes Cdst (residual
// stream, fp32) AND lnout = LayerNorm(row)*g+b as bf16.
__device__ __forceinline__ float gelu_exact(float x) {
    return 0.5f * x * (1.0f + erff(x * 0.70710678118654752f));
}

template<int K, int N, bool BIAS, bool RES, bool GELU, bool OBF, bool LNOUT>
__global__ __launch_bounds__(256) void gemm_bf16(
    const __hip_bfloat16* __restrict__ A, const __hip_bfloat16* __restrict__ Bt,
    const float* __restrict__ bias, const float* __restrict__ Rsrc,
    void* __restrict__ Cdst,
    const float* __restrict__ lng, const float* __restrict__ lnb,
    __hip_bfloat16* __restrict__ lnout)
{
    __shared__ unsigned short As[64 * 128];    // 16 KB
    __shared__ unsigned short Bs[128 * 128];   // 32 KB
    int tid = threadIdx.x;
    int l = tid & 63, w = tid >> 6;
    int wr = w >> 1, wc = w & 1;
    int lr = l & 15, q = l >> 4;
    int m0 = blockIdx.y * 64;
    int n0 = blockIdx.x * 128;

    f32x4 acc[2][4];
    #pragma unroll
    for (int mt = 0; mt < 2; ++mt)
        #pragma unroll
        for (int nt = 0; nt < 4; ++nt) acc[mt][nt] = (f32x4){0.f, 0.f, 0.f, 0.f};

    for (int kt = 0; kt < K; kt += 128) {
        if (kt) __syncthreads();
        #pragma unroll
        for (int p = 0; p < 4; ++p) {
            int n = p * 256 + tid;
            int r = n >> 4;
            int c = (n & 15) ^ (r & 7);
            uint4 dv = *(const uint4*)(A + (size_t)(m0 + r) * K + kt + c * 8);
            *(uint4*)&As[n * 8] = dv;
        }
        #pragma unroll
        for (int p = 0; p < 8; ++p) {
            int n = p * 256 + tid;
            int r = n >> 4;
            int c = (n & 15) ^ (r & 7);
            uint4 dv = *(const uint4*)(Bt + (size_t)(n0 + r) * K + kt + c * 8);
            *(uint4*)&Bs[n * 8] = dv;
        }
        __syncthreads();

        #pragma unroll
        for (int kk = 0; kk < 4; ++kk) {
            bf16x8 afr[2], bfr[4];
            #pragma unroll
            for (int mt = 0; mt < 2; ++mt) {
                int rA = wr * 32 + mt * 16 + lr;
                int cc = (kk * 4 + q) ^ (rA & 7);
                afr[mt] = *(const bf16x8*)&As[(rA * 16 + cc) * 8];
            }
            #pragma unroll
            for (int nt = 0; nt < 4; ++nt) {
                int rB = wc * 64 + nt * 16 + lr;
                int cc = (kk * 4 + q) ^ (rB & 7);
                bfr[nt] = *(const bf16x8*)&Bs[(rB * 16 + cc) * 8];
            }
            #pragma unroll
            for (int mt = 0; mt < 2; ++mt)
                #pragma unroll
                for (int nt = 0; nt < 4; ++nt)
                    acc[mt][nt] = __builtin_amdgcn_mfma_f32_16x16x32_bf16(
                        afr[mt], bfr[nt], acc[mt][nt], 0, 0, 0);
        }
    }

    if (!LNOUT) {
        // C layout: col=lane&15, row=(lane>>4)*4+reg
        #pragma unroll
        for (int mt = 0; mt < 2; ++mt) {
            #pragma unroll
            for (int nt = 0; nt < 4; ++nt) {
                int col = n0 + wc * 64 + nt * 16 + lr;
                float bv = BIAS ? bias[col] : 0.f;
                #pragma unroll
                for (int r = 0; r < 4; ++r) {
                    int row = m0 + wr * 32 + mt * 16 + q * 4 + r;
                    float val = acc[mt][nt][r] + bv;
                    if (GELU) val = gelu_exact(val);
                    if (RES) val += Rsrc[(size_t)row * N + col];
                    if (OBF) ((__hip_bfloat16*)Cdst)[(size_t)row * N + col] = __float2bfloat16(val);
                    else     ((float*)Cdst)[(size_t)row * N + col] = val;
                }
            }
        }
    } else {
        float* fp = (float*)Bs;    // 64 x 128 fp32 tile = 32 KB (Bs reused)
        __syncthreads();           // all waves done reading As/Bs
        #pragma unroll
        for (int mt = 0; mt < 2; ++mt) {
            #pragma unroll
            for (int nt = 0; nt < 4; ++nt) {
                int col = wc * 64 + nt * 16 + lr;
                float bv = BIAS ? bias[col] : 0.f;
                #pragma unroll
                for (int r = 0; r < 4; ++r) {
                    int rowL = wr * 32 + mt * 16 + q * 4 + r;
                    float val = acc[mt][nt][r] + bv;
                    if (RES) val += Rsrc[(size_t)(m0 + rowL) * N + col];
                    fp[rowL * 128 + col] = val;
                }
            }
        }
        __syncthreads();
        int rl = tid >> 2, sub = tid & 3;          // 64 rows x 4 col-groups
        float s = 0.f, sq = 0.f;
        #pragma unroll
        for (int c4 = 0; c4 < 8; ++c4) {
            float4 v = *(const float4*)&fp[rl * 128 + sub * 32 + c4 * 4];
            s  += (v.x + v.y) + (v.z + v.w);
            sq += (v.x * v.x + v.y * v.y) + (v.z * v.z + v.w * v.w);
        }
        s  += __shfl_xor(s, 1);  s  += __shfl_xor(s, 2);
        sq += __shfl_xor(sq, 1); sq += __shfl_xor(sq, 2);
        float mean = s * (1.0f / 128.0f);
        float var  = sq * (1.0f / 128.0f) - mean * mean;
        float rstd = rsqrtf(var + 1e-5f);
        int rowG = m0 + rl;
        #pragma unroll
        for (int c4 = 0; c4 < 8; ++c4) {
            int col = sub * 32 + c4 * 4;
            float4 v  = *(const float4*)&fp[rl * 128 + col];
            float4 g4 = *(const float4*)(lng + col);
            float4 b4 = *(const float4*)(lnb + col);
            *(float4*)((float*)Cdst + (size_t)rowG * 128 + col) = v;   // residual stream
            unsigned short pk[4];
            pk[0] = f2bs((v.x - mean) * rstd * g4.x + b4.x);
            pk[1] = f2bs((v.y - mean) * rstd * g4.y + b4.y);
            pk[2] = f2bs((v.z - mean) * rstd * g4.z + b4.z);
            pk[3] = f2bs((v.w - mean) * rstd * g4.w + b4.w);
            *(ushort4*)((unsigned short*)lnout + (size_t)rowG * 128 + col) = *(ushort4*)&pk[0];
        }
    }
}

// ---------------- attention: MFMA flash-style (unchanged from round 7) ----------------
__global__ __launch_bounds__(256) void attn_kernel(
    const float* __restrict__ qkv, __hip_bfloat16* __restrict__ o)
{
    int z  = blockIdx.x & 1;
    int bh = blockIdx.x >> 1;
    int b = bh >> 3, hh = bh & 7;
    const float* base = qkv + (size_t)b * LL * 256 + hh * DHH;

    __shared__ unsigned short knb[LL + 2][24];   // qhat/khat bf16; cols 16..23 zeroed
    __shared__ unsigned short vtb[16][LL + 24];  // V^T bf16; cols 384..407 zeroed
    __shared__ float cq[LL];                     // 0.25*|q|
    __shared__ unsigned short ptile[4][16][40];  // per-wave P tile; cols 16..31 zeroed

    int t = threadIdx.x;
    for (int r = t; r < LL; r += 256) {
        const float* qp = base + (size_t)r * 256;
        float q[16], vv[16];
        #pragma unroll
        for (int c = 0; c < 4; ++c) {
            *(float4*)&q[c * 4]  = *(const float4*)(qp + c * 4);
            *(float4*)&vv[c * 4] = *(const float4*)(qp + 128 + c * 4);
        }
        float nrm = 0.f;
        #pragma unroll
        for (int d = 0; d < 16; ++d) nrm = fmaf(q[d], q[d], nrm);
        float qn = sqrtf(nrm);
        float inv = 1.0f / fmaxf(qn, 1e-12f);
        cq[r] = 0.25f * qn;
        unsigned short kb[16];
        #pragma unroll
        for (int d = 0; d < 16; ++d) kb[d] = f2bs(q[d] * inv);
        *(uint4*)&knb[r][0] = *(uint4*)&kb[0];
        *(uint4*)&knb[r][8] = *(uint4*)&kb[8];
        *(uint4*)&knb[r][16] = make_uint4(0u, 0u, 0u, 0u);
        #pragma unroll
        for (int d = 0; d < 16; ++d) vtb[d][r] = f2bs(vv[d]);
    }
    if (t < 16) {
        #pragma unroll
        for (int c = 0; c < 24; ++c) vtb[t][LL + c] = 0;
    }

    int w = t >> 6, l = t & 63;
    int lr = l & 15, q4 = l >> 4;
    *(uint2*)&ptile[w][lr][16 + q4 * 4] = make_uint2(0u, 0u);
    __syncthreads();

    bf16x8 zfrag = {0, 0, 0, 0, 0, 0, 0, 0};
    bf16x8 onesf;
    #pragma unroll
    for (int i = 0; i < 8; ++i) onesf[i] = (short)0x3F80;

    int slot = 2 * w + z;
    int strips[3] = { slot, 15 - slot, 16 + slot };
    #pragma unroll
    for (int si = 0; si < 3; ++si) {
        int s = strips[si];
        int r0 = s * 16;
        bf16x8 afrag = *(const bf16x8*)&knb[r0 + lr][(q4 & 1) * 8];
        afrag = (q4 < 2) ? afrag : zfrag;
        float ccv[4];
        #pragma unroll
        for (int reg = 0; reg < 4; ++reg) ccv[reg] = cq[r0 + q4 * 4 + reg];

        f32x4 oacc = (f32x4){0.f, 0.f, 0.f, 0.f};
        f32x4 lacc = (f32x4){0.f, 0.f, 0.f, 0.f};

        for (int jt = 0; jt <= s; ++jt) {
            bf16x8 bfrag = *(const bf16x8*)&knb[jt * 16 + lr][q4 * 8];
            f32x4 sacc = __builtin_amdgcn_mfma_f32_16x16x32_bf16(
                afrag, bfrag, (f32x4){0.f, 0.f, 0.f, 0.f}, 0, 0, 0);
            int colg = jt * 16 + lr;
            #pragma unroll
            for (int reg = 0; reg < 4; ++reg) {
                int rowg = r0 + q4 * 4 + reg;
                float pe = __expf(fmaf(sacc[reg], ccv[reg], -ccv[reg]));
                pe = (colg < rowg) ? pe : 0.f;
                ptile[w][q4 * 4 + reg][lr] = f2bs(pe);
            }
            asm volatile("s_waitcnt lgkmcnt(0)" ::: "memory");
            bf16x8 pfrag = *(const bf16x8*)&ptile[w][lr][q4 * 8];
            bf16x8 vfrag = *(const bf16x8*)&vtb[lr][jt * 16 + q4 * 8];
            oacc = __builtin_amdgcn_mfma_f32_16x16x32_bf16(pfrag, vfrag, oacc, 0, 0, 0);
            lacc = __builtin_amdgcn_mfma_f32_16x16x32_bf16(pfrag, onesf, lacc, 0, 0, 0);
        }

        if (s == 0 && q4 == 0) {
            lacc[0] = 1.0f;
            oacc[0] = bs2f(vtb[lr][0]);
        }
        unsigned short* ob = (unsigned short*)o + (size_t)(b * LL + r0) * DD + hh * 16 + lr;
        #pragma unroll
        for (int reg = 0; reg < 4; ++reg) {
            float ov = oacc[reg] / lacc[reg];
            ob[(size_t)(q4 * 4 + reg) * DD] = f2bs(ov);
        }
    }
}

// ---------------- final projection [64,49152] x [49152,128] ----------------
__global__ __launch_bounds__(256) void out_init_kernel(
    const float* __restrict__ bp, float* __restrict__ out)
{
    int t = blockIdx.x * 256 + threadIdx.x;   // 8192
    out[t] = bp[t & (COUT - 1)];
}

// v3: waves split K within the block (Wp read once, coalesced), x broadcast from
// LDS, cross-wave LDS reduce, then one atomicAdd set per block.
__global__ __launch_bounds__(256) void final_gemm_kernel(
    const float* __restrict__ xm, const float* __restrict__ Wp,
    float* __restrict__ out)
{
    int mq = blockIdx.x;        // 0..3 -> rows mq*16..+15
    int kc = blockIdx.y;        // 0..95 -> k chunk of 512
    __shared__ float xs[16][520];
    int k0 = kc * 512;
    #pragma unroll
    for (int p = 0; p < 8; ++p) {
        int id = threadIdx.x + p * 256;   // 0..2047 float4s
        int r = id >> 7;
        int c = (id & 127) << 2;
        *(float4*)&xs[r][c] = *(const float4*)(xm + (size_t)(mq * 16 + r) * KP + k0 + c);
    }
    __syncthreads();

    int w = threadIdx.x >> 6, lane = threadIdx.x & 63;
    float acc[16][2];
    #pragma unroll
    for (int r = 0; r < 16; ++r) { acc[r][0] = 0.f; acc[r][1] = 0.f; }

    const float* wbase = Wp + (size_t)(k0 + w * 128) * COUT + 2 * lane;
    for (int ks = 0; ks < 128; ks += 4) {
        float2 wv0 = *(const float2*)(wbase + (size_t)(ks + 0) * COUT);
        float2 wv1 = *(const float2*)(wbase + (size_t)(ks + 1) * COUT);
        float2 wv2 = *(const float2*)(wbase + (size_t)(ks + 2) * COUT);
        float2 wv3 = *(const float2*)(wbase + (size_t)(ks + 3) * COUT);
        #pragma unroll
        for (int r = 0; r < 16; ++r) {
            float4 xv = *(const float4*)&xs[r][w * 128 + ks];
            acc[r][0] = fmaf(xv.x, wv0.x, acc[r][0]);
            acc[r][1] = fmaf(xv.x, wv0.y, acc[r][1]);
            acc[r][0] = fmaf(xv.y, wv1.x, acc[r][0]);
            acc[r][1] = fmaf(xv.y, wv1.y, acc[r][1]);
            acc[r][0] = fmaf(xv.z, wv2.x, acc[r][0]);
            acc[r][1] = fmaf(xv.z, wv2.y, acc[r][1]);
            acc[r][0] = fmaf(xv.w, wv3.x, acc[r][0]);
            acc[r][1] = fmaf(xv.w, wv3.y, acc[r][1]);
        }
    }

    // cross-wave reduce via LDS (xs reused: need 8192 floats, have 8320)
    float* fp = (float*)xs;
    __syncthreads();
    #pragma unroll
    for (int r = 0; r < 16; ++r)
        *(float2*)&fp[w * 2048 + r * 128 + 2 * lane] = make_float2(acc[r][0], acc[r][1]);
    __syncthreads();
    int j0 = threadIdx.x * 8;
    #pragma unroll
    for (int g = 0; g < 2; ++g) {
        int j = j0 + g * 4;
        float4 s0 = *(const float4*)&fp[j];
        float4 s1 = *(const float4*)&fp[2048 + j];
        float4 s2 = *(const float4*)&fp[4096 + j];
        float4 s3 = *(const float4*)&fp[6144 + j];
        float4 sm = make_float4((s0.x + s1.x) + (s2.x + s3.x),
                                (s0.y + s1.y) + (s2.y + s3.y),
                                (s0.z + s1.z) + (s2.z + s3.z),
                                (s0.w + s1.w) + (s2.w + s3.w));
        int r = j >> 7, c = j & 127;
        float* op = out + (size_t)(mq * 16 + r) * COUT + c;
        atomicAdd(op + 0, sm.x);
        atomicAdd(op + 1, sm.y);
        atomicAdd(op + 2, sm.z);
        atomicAdd(op + 3, sm.w);
    }
}

// ---------------- launch ----------------
extern "C" void kernel_launch(void* const* d_in, const int* in_sizes, int n_in,
                              void* d_out, int out_size, void* d_ws, size_t ws_size,
                              hipStream_t stream)
{
    const int*   x_enc = (const int*)  d_in[0];
    const float* emb   = (const float*)d_in[1];
    const float* pos1  = (const float*)d_in[2];
    const float* pos2  = (const float*)d_in[3];
    const float* ln1_g = (const float*)d_in[4];
    const float* ln1_b = (const float*)d_in[5];
    const float* Wqk   = (const float*)d_in[6];
    const float* Wv    = (const float*)d_in[7];
    const float* Wo    = (const float*)d_in[8];
    const float* bo    = (const float*)d_in[9];
    const float* ln2_g = (const float*)d_in[10];
    const float* ln2_b = (const float*)d_in[11];
    const float* W1    = (const float*)d_in[12];
    const float* b1    = (const float*)d_in[13];
    const float* W2    = (const float*)d_in[14];
    const float* b2    = (const float*)d_in[15];
    const float* lnf_g = (const float*)d_in[16];
    const float* lnf_b = (const float*)d_in[17];
    const float* Wp    = (const float*)d_in[18];
    const float* bp    = (const float*)d_in[19];
    float* out = (float*)d_out;

    // workspace layout; SZ = 3,145,728 elements
    const size_t SZ = (size_t)MROWS * DD;
    float* ws_f = (float*)d_ws;
    float* x1 = ws_f;                    // fp32 [M,128]
    float* x2 = ws_f + SZ;               // fp32 [M,128]
    float* R  = ws_f + 2 * SZ;           // 2*SZ floats shared region
    float* qkv = R;                      // fp32 [M,256]  (lifetime: qkv-gemm..attn)
    __hip_bfloat16* hff = (__hip_bfloat16*)R;   // bf16 [M,512] (lifetime: ff1..ff2)
    float* hfin = R;                     // fp32 [M,128]  (final LN out)
    __hip_bfloat16* h_bf = (__hip_bfloat16*)(ws_f + 4 * SZ);  // bf16 [M,128]
    __hip_bfloat16* o_bf = h_bf + SZ;                          // bf16 [M,128]
    __hip_bfloat16* wqvT = o_bf + SZ;    // 6 * [256,128]
    __hip_bfloat16* woT  = wqvT + 6 * 32768;         // 6 * [128,128]
    __hip_bfloat16* w1T  = woT  + 6 * 16384;         // 6 * [512,128]
    __hip_bfloat16* w2T  = w1T  + 6 * 65536;         // 6 * [128,512]

    castT_kernel<<<dim3(4, 4, 6),  dim3(256), 0, stream>>>(Wqk, wqvT,         128, 128, 16384, 32768);
    castT_kernel<<<dim3(4, 4, 6),  dim3(256), 0, stream>>>(Wv,  wqvT + 16384, 128, 128, 16384, 32768);
    castT_kernel<<<dim3(4, 4, 6),  dim3(256), 0, stream>>>(Wo,  woT,          128, 128, 16384, 16384);
    castT_kernel<<<dim3(4, 16, 6), dim3(256), 0, stream>>>(W1,  w1T,          128, 512, 65536, 65536);
    castT_kernel<<<dim3(16, 4, 6), dim3(256), 0, stream>>>(W2,  w2T,          512, 128, 65536, 65536);

    embed_kernel<<<dim3(MROWS * 32 / 256), dim3(256), 0, stream>>>(x_enc, emb, pos1, pos2, x1, x2);
    // layer-0 ln1 (subsequent ln1/ln2 are fused into ff2/wo epilogues)
    ln_kernel<<<dim3(MROWS / 4), dim3(256), 0, stream>>>(x2, ln1_g, ln1_b, h_bf);

    for (int d = 0; d < DEPTH; ++d) {
        const float* bod = bo + d * DD;
        const float* l2g = ln2_g + d * DD;
        const float* l2b = ln2_b + d * DD;
        const float* b1d = b1 + d * FFD;
        const float* b2d = b2 + d * DD;
        const __hip_bfloat16* wqv_d = wqvT + (size_t)d * 32768;
        const __hip_bfloat16* wo_d  = woT  + (size_t)d * 16384;
        const __hip_bfloat16* w1_d  = w1T  + (size_t)d * 65536;
        const __hip_bfloat16* w2_d  = w2T  + (size_t)d * 65536;

        gemm_bf16<128, 256, false, false, false, false, false>
            <<<dim3(2, MROWS / 64), dim3(256), 0, stream>>>(
                h_bf, wqv_d, nullptr, nullptr, qkv, nullptr, nullptr, nullptr);
        attn_kernel<<<dim3(BB * HH * 2), dim3(256), 0, stream>>>(qkv, o_bf);
        // x1 += o@Wo + bo ; h_bf = LN2(x1)   (fused)
        gemm_bf16<128, 128, true, true, false, false, true>
            <<<dim3(1, MROWS / 64), dim3(256), 0, stream>>>(
                o_bf, wo_d, bod, x1, x1, l2g, l2b, h_bf);
        gemm_bf16<128, 512, true, false, true, true, false>
            <<<dim3(4, MROWS / 64), dim3(256), 0, stream>>>(
                h_bf, w1_d, b1d, nullptr, hff, nullptr, nullptr, nullptr);
        if (d < DEPTH - 1) {
            // x2 += hff@W2 + b2 ; h_bf = LN1[d+1](x2)   (fused)
            gemm_bf16<512, 128, true, true, false, false, true>
                <<<dim3(1, MROWS / 64), dim3(256), 0, stream>>>(
                    hff, w2_d, b2d, x2, x2, ln1_g + (d + 1) * DD, ln1_b + (d + 1) * DD, h_bf);
        } else {
            gemm_bf16<512, 128, true, true, false, false, false>
                <<<dim3(1, MROWS / 64), dim3(256), 0, stream>>>(
                    hff, w2_d, b2d, x2, x2, nullptr, nullptr, nullptr);
        }
    }

    avgln_kernel<<<dim3(MROWS / 4), dim3(256), 0, stream>>>(x1, x2, lnf_g, lnf_b, hfin);
    out_init_kernel<<<dim3(32), dim3(256), 0, stream>>>(bp, out);
    final_gemm_kernel<<<dim3(4, 96), dim3(256), 0, stream>>>(hfin, Wp, out);
}

// Round 9
// 709.739 us; speedup vs baseline: 1.0138x; 1.0138x over previous
//
#include <hip/hip_runtime.h>
#include <hip/hip_bf16.h>
#include <math.h>

#define BB 64
#define LL 384
#define DD 128
#define HH 8
#define DHH 16
#define DEPTH 6
#define FFD 512
#define MROWS (BB*LL)      // 24576
#define COUT 128
#define KP (LL*DD)         // 49152

typedef short bf16x8 __attribute__((ext_vector_type(8)));
typedef float f32x4 __attribute__((ext_vector_type(4)));

__device__ __forceinline__ unsigned short f2bs(float x) {
    __hip_bfloat16 h = __float2bfloat16(x);
    return *reinterpret_cast<unsigned short*>(&h);
}
__device__ __forceinline__ float bs2f(unsigned short u) {
    unsigned int v = ((unsigned int)u) << 16;
    return __uint_as_float(v);
}

// ---------------- embed + axial pos ----------------
__global__ __launch_bounds__(256) void embed_kernel(
    const int* __restrict__ x_enc, const float* __restrict__ emb,
    const float* __restrict__ pos1, const float* __restrict__ pos2,
    float* __restrict__ x1, float* __restrict__ x2)
{
    int t = blockIdx.x * 256 + threadIdx.x;      // over MROWS * 32 float4
    int row = t >> 5;
    int c4 = t & 31;
    int l = row % LL;
    int tok = x_enc[row];
    float4 a = ((const float4*)(emb + (size_t)tok * DD))[c4];
    float4 b = ((const float4*)(pos1 + (l / 25) * DD))[c4];
    float4 c = ((const float4*)(pos2 + (l % 25) * DD))[c4];
    float4 r = make_float4(a.x + b.x + c.x, a.y + b.y + c.y,
                           a.z + b.z + c.z, a.w + b.w + c.w);
    ((float4*)x1)[t] = r;
    ((float4*)x2)[t] = r;
}

// ---------------- weight cast + transpose: W[K,N] fp32 -> Wt[N,K] bf16 ----------------
__global__ __launch_bounds__(256) void castT_kernel(
    const float* __restrict__ src, __hip_bfloat16* __restrict__ dst, int K, int N,
    long sstride, long dstride)
{
    __shared__ float tile[32][33];
    int kb = blockIdx.x * 32, nb = blockIdx.y * 32;
    int tx = threadIdx.x & 31, ty = threadIdx.x >> 5;   // ty 0..7
    const float* s = src + (size_t)blockIdx.z * sstride;
    __hip_bfloat16* d = dst + (size_t)blockIdx.z * dstride;
    #pragma unroll
    for (int r = 0; r < 32; r += 8)
        tile[r + ty][tx] = s[(size_t)(kb + r + ty) * N + nb + tx];
    __syncthreads();
    #pragma unroll
    for (int r = 0; r < 32; r += 8)
        d[(size_t)(nb + r + ty) * K + kb + tx] = __float2bfloat16(tile[tx][r + ty]);
}

// ---------------- LayerNorm (wave per row) -> bf16 out (layer-0 ln1 only) ----------------
__global__ __launch_bounds__(256) void ln_kernel(
    const float* __restrict__ x, const float* __restrict__ g,
    const float* __restrict__ b, __hip_bfloat16* __restrict__ y)
{
    int wave = threadIdx.x >> 6;
    int lane = threadIdx.x & 63;
    int row = blockIdx.x * 4 + wave;
    float2 v = ((const float2*)(x + (size_t)row * DD))[lane];
    float2 gg = ((const float2*)g)[lane];
    float2 bb = ((const float2*)b)[lane];
    float s = v.x + v.y;
    float sq = v.x * v.x + v.y * v.y;
    #pragma unroll
    for (int off = 32; off > 0; off >>= 1) {
        s += __shfl_down(s, off, 64);
        sq += __shfl_down(sq, off, 64);
    }
    s = __shfl(s, 0, 64);
    sq = __shfl(sq, 0, 64);
    float mean = s * (1.0f / DD);
    float var = sq * (1.0f / DD) - mean * mean;
    float rstd = rsqrtf(var + 1e-5f);
    __hip_bfloat16* yp = y + (size_t)row * DD + lane * 2;
    yp[0] = __float2bfloat16((v.x - mean) * rstd * gg.x + bb.x);
    yp[1] = __float2bfloat16((v.y - mean) * rstd * gg.y + bb.y);
}

// avg + LN -> fp32 out (for final projection)
__global__ __launch_bounds__(256) void avgln_kernel(
    const float* __restrict__ xa, const float* __restrict__ xb,
    const float* __restrict__ g, const float* __restrict__ b, float* __restrict__ y)
{
    int wave = threadIdx.x >> 6;
    int lane = threadIdx.x & 63;
    int row = blockIdx.x * 4 + wave;
    float2 va = ((const float2*)(xa + (size_t)row * DD))[lane];
    float2 vb = ((const float2*)(xb + (size_t)row * DD))[lane];
    float2 v = make_float2((va.x + vb.x) * 0.5f, (va.y + vb.y) * 0.5f);
    float2 gg = ((const float2*)g)[lane];
    float2 bb = ((const float2*)b)[lane];
    float s = v.x + v.y;
    float sq = v.x * v.x + v.y * v.y;
    #pragma unroll
    for (int off = 32; off > 0; off >>= 1) {
        s += __shfl_down(s, off, 64);
        sq += __shfl_down(sq, off, 64);
    }
    s = __shfl(s, 0, 64);
    sq = __shfl(sq, 0, 64);
    float mean = s * (1.0f / DD);
    float var = sq * (1.0f / DD) - mean * mean;
    float rstd = rsqrtf(var + 1e-5f);
    float2 o;
    o.x = (v.x - mean) * rstd * gg.x + bb.x;
    o.y = (v.y - mean) * rstd * gg.y + bb.y;
    ((float2*)(y + (size_t)row * DD))[lane] = o;
}

// ---------------- bf16 MFMA GEMM (optional fused row-LayerNorm epilogue) ----------------
__device__ __forceinline__ float gelu_exact(float x) {
    return 0.5f * x * (1.0f + erff(x * 0.70710678118654752f));
}

template<int K, int N, bool BIAS, bool RES, bool GELU, bool OBF, bool LNOUT>
__global__ __launch_bounds__(256) void gemm_bf16(
    const __hip_bfloat16* __restrict__ A, const __hip_bfloat16* __restrict__ Bt,
    const float* __restrict__ bias, const float* __restrict__ Rsrc,
    void* __restrict__ Cdst,
    const float* __restrict__ lng, const float* __restrict__ lnb,
    __hip_bfloat16* __restrict__ lnout)
{
    __shared__ unsigned short As[64 * 128];    // 16 KB
    __shared__ unsigned short Bs[128 * 128];   // 32 KB
    int tid = threadIdx.x;
    int l = tid & 63, w = tid >> 6;
    int wr = w >> 1, wc = w & 1;
    int lr = l & 15, q = l >> 4;
    int m0 = blockIdx.y * 64;
    int n0 = blockIdx.x * 128;

    f32x4 acc[2][4];
    #pragma unroll
    for (int mt = 0; mt < 2; ++mt)
        #pragma unroll
        for (int nt = 0; nt < 4; ++nt) acc[mt][nt] = (f32x4){0.f, 0.f, 0.f, 0.f};

    for (int kt = 0; kt < K; kt += 128) {
        if (kt) __syncthreads();
        #pragma unroll
        for (int p = 0; p < 4; ++p) {
            int n = p * 256 + tid;
            int r = n >> 4;
            int c = (n & 15) ^ (r & 7);
            uint4 dv = *(const uint4*)(A + (size_t)(m0 + r) * K + kt + c * 8);
            *(uint4*)&As[n * 8] = dv;
        }
        #pragma unroll
        for (int p = 0; p < 8; ++p) {
            int n = p * 256 + tid;
            int r = n >> 4;
            int c = (n & 15) ^ (r & 7);
            uint4 dv = *(const uint4*)(Bt + (size_t)(n0 + r) * K + kt + c * 8);
            *(uint4*)&Bs[n * 8] = dv;
        }
        __syncthreads();

        #pragma unroll
        for (int kk = 0; kk < 4; ++kk) {
            bf16x8 afr[2], bfr[4];
            #pragma unroll
            for (int mt = 0; mt < 2; ++mt) {
                int rA = wr * 32 + mt * 16 + lr;
                int cc = (kk * 4 + q) ^ (rA & 7);
                afr[mt] = *(const bf16x8*)&As[(rA * 16 + cc) * 8];
            }
            #pragma unroll
            for (int nt = 0; nt < 4; ++nt) {
                int rB = wc * 64 + nt * 16 + lr;
                int cc = (kk * 4 + q) ^ (rB & 7);
                bfr[nt] = *(const bf16x8*)&Bs[(rB * 16 + cc) * 8];
            }
            #pragma unroll
            for (int mt = 0; mt < 2; ++mt)
                #pragma unroll
                for (int nt = 0; nt < 4; ++nt)
                    acc[mt][nt] = __builtin_amdgcn_mfma_f32_16x16x32_bf16(
                        afr[mt], bfr[nt], acc[mt][nt], 0, 0, 0);
        }
    }

    if (!LNOUT) {
        #pragma unroll
        for (int mt = 0; mt < 2; ++mt) {
            #pragma unroll
            for (int nt = 0; nt < 4; ++nt) {
                int col = n0 + wc * 64 + nt * 16 + lr;
                float bv = BIAS ? bias[col] : 0.f;
                #pragma unroll
                for (int r = 0; r < 4; ++r) {
                    int row = m0 + wr * 32 + mt * 16 + q * 4 + r;
                    float val = acc[mt][nt][r] + bv;
                    if (GELU) val = gelu_exact(val);
                    if (RES) val += Rsrc[(size_t)row * N + col];
                    if (OBF) ((__hip_bfloat16*)Cdst)[(size_t)row * N + col] = __float2bfloat16(val);
                    else     ((float*)Cdst)[(size_t)row * N + col] = val;
                }
            }
        }
    } else {
        float* fp = (float*)Bs;    // 64 x 128 fp32 tile = 32 KB (Bs reused)
        __syncthreads();           // all waves done reading As/Bs
        #pragma unroll
        for (int mt = 0; mt < 2; ++mt) {
            #pragma unroll
            for (int nt = 0; nt < 4; ++nt) {
                int col = wc * 64 + nt * 16 + lr;
                float bv = BIAS ? bias[col] : 0.f;
                #pragma unroll
                for (int r = 0; r < 4; ++r) {
                    int rowL = wr * 32 + mt * 16 + q * 4 + r;
                    float val = acc[mt][nt][r] + bv;
                    if (RES) val += Rsrc[(size_t)(m0 + rowL) * N + col];
                    fp[rowL * 128 + col] = val;
                }
            }
        }
        __syncthreads();
        int rl = tid >> 2, sub = tid & 3;          // 64 rows x 4 col-groups
        float s = 0.f, sq = 0.f;
        #pragma unroll
        for (int c4 = 0; c4 < 8; ++c4) {
            float4 v = *(const float4*)&fp[rl * 128 + sub * 32 + c4 * 4];
            s  += (v.x + v.y) + (v.z + v.w);
            sq += (v.x * v.x + v.y * v.y) + (v.z * v.z + v.w * v.w);
        }
        s  += __shfl_xor(s, 1);  s  += __shfl_xor(s, 2);
        sq += __shfl_xor(sq, 1); sq += __shfl_xor(sq, 2);
        float mean = s * (1.0f / 128.0f);
        float var  = sq * (1.0f / 128.0f) - mean * mean;
        float rstd = rsqrtf(var + 1e-5f);
        int rowG = m0 + rl;
        #pragma unroll
        for (int c4 = 0; c4 < 8; ++c4) {
            int col = sub * 32 + c4 * 4;
            float4 v  = *(const float4*)&fp[rl * 128 + col];
            float4 g4 = *(const float4*)(lng + col);
            float4 b4 = *(const float4*)(lnb + col);
            *(float4*)((float*)Cdst + (size_t)rowG * 128 + col) = v;   // residual stream
            unsigned short pk[4];
            pk[0] = f2bs((v.x - mean) * rstd * g4.x + b4.x);
            pk[1] = f2bs((v.y - mean) * rstd * g4.y + b4.y);
            pk[2] = f2bs((v.z - mean) * rstd * g4.z + b4.z);
            pk[3] = f2bs((v.w - mean) * rstd * g4.w + b4.w);
            *(ushort4*)((unsigned short*)lnout + (size_t)rowG * 128 + col) = *(ushort4*)&pk[0];
        }
    }
}

// ---------------- attention: MFMA flash-style, bf16 qkv input ----------------
// Pair blocks (z=0/1) for one (b,h) are 512 apart (512%8==0 -> same XCD -> L2 reuse).
__global__ __launch_bounds__(256) void attn_kernel(
    const __hip_bfloat16* __restrict__ qkv, __hip_bfloat16* __restrict__ o)
{
    int z  = blockIdx.x >> 9;
    int bh = blockIdx.x & 511;
    int b = bh >> 3, hh = bh & 7;
    const unsigned short* base = (const unsigned short*)qkv + (size_t)b * LL * 256 + hh * DHH;

    __shared__ unsigned short knb[LL + 2][24];   // qhat/khat bf16; cols 16..23 zeroed
    __shared__ unsigned short vtb[16][LL + 24];  // V^T bf16; cols 384..407 zeroed
    __shared__ float cq[LL];                     // 0.25*|q|
    __shared__ unsigned short ptile[4][16][40];  // per-wave P tile; cols 16..31 zeroed

    int t = threadIdx.x;
    for (int r = t; r < LL; r += 256) {
        const unsigned short* qp = base + (size_t)r * 256;
        unsigned short qs[16], vs16[16];
        *(uint4*)&qs[0]  = *(const uint4*)(qp);
        *(uint4*)&qs[8]  = *(const uint4*)(qp + 8);
        *(uint4*)&vs16[0] = *(const uint4*)(qp + 128);
        *(uint4*)&vs16[8] = *(const uint4*)(qp + 136);
        float q[16];
        #pragma unroll
        for (int d = 0; d < 16; ++d) q[d] = bs2f(qs[d]);
        float nrm = 0.f;
        #pragma unroll
        for (int d = 0; d < 16; ++d) nrm = fmaf(q[d], q[d], nrm);
        float qn = sqrtf(nrm);
        float inv = 1.0f / fmaxf(qn, 1e-12f);
        cq[r] = 0.25f * qn;
        unsigned short kb[16];
        #pragma unroll
        for (int d = 0; d < 16; ++d) kb[d] = f2bs(q[d] * inv);
        *(uint4*)&knb[r][0] = *(uint4*)&kb[0];
        *(uint4*)&knb[r][8] = *(uint4*)&kb[8];
        *(uint4*)&knb[r][16] = make_uint4(0u, 0u, 0u, 0u);
        #pragma unroll
        for (int d = 0; d < 16; ++d) vtb[d][r] = vs16[d];
    }
    if (t < 16) {
        #pragma unroll
        for (int c = 0; c < 24; ++c) vtb[t][LL + c] = 0;
    }

    int w = t >> 6, l = t & 63;
    int lr = l & 15, q4 = l >> 4;
    *(uint2*)&ptile[w][lr][16 + q4 * 4] = make_uint2(0u, 0u);
    __syncthreads();

    bf16x8 zfrag = {0, 0, 0, 0, 0, 0, 0, 0};
    bf16x8 onesf;
    #pragma unroll
    for (int i = 0; i < 8; ++i) onesf[i] = (short)0x3F80;

    int slot = 2 * w + z;
    int strips[3] = { slot, 15 - slot, 16 + slot };
    #pragma unroll
    for (int si = 0; si < 3; ++si) {
        int s = strips[si];
        int r0 = s * 16;
        bf16x8 afrag = *(const bf16x8*)&knb[r0 + lr][(q4 & 1) * 8];
        afrag = (q4 < 2) ? afrag : zfrag;
        float ccv[4];
        #pragma unroll
        for (int reg = 0; reg < 4; ++reg) ccv[reg] = cq[r0 + q4 * 4 + reg];

        f32x4 oacc = (f32x4){0.f, 0.f, 0.f, 0.f};
        f32x4 lacc = (f32x4){0.f, 0.f, 0.f, 0.f};

        for (int jt = 0; jt <= s; ++jt) {
            bf16x8 bfrag = *(const bf16x8*)&knb[jt * 16 + lr][q4 * 8];
            f32x4 sacc = __builtin_amdgcn_mfma_f32_16x16x32_bf16(
                afrag, bfrag, (f32x4){0.f, 0.f, 0.f, 0.f}, 0, 0, 0);
            int colg = jt * 16 + lr;
            #pragma unroll
            for (int reg = 0; reg < 4; ++reg) {
                int rowg = r0 + q4 * 4 + reg;
                float pe = __expf(fmaf(sacc[reg], ccv[reg], -ccv[reg]));
                pe = (colg < rowg) ? pe : 0.f;
                ptile[w][q4 * 4 + reg][lr] = f2bs(pe);
            }
            asm volatile("s_waitcnt lgkmcnt(0)" ::: "memory");
            bf16x8 pfrag = *(const bf16x8*)&ptile[w][lr][q4 * 8];
            bf16x8 vfrag = *(const bf16x8*)&vtb[lr][jt * 16 + q4 * 8];
            oacc = __builtin_amdgcn_mfma_f32_16x16x32_bf16(pfrag, vfrag, oacc, 0, 0, 0);
            lacc = __builtin_amdgcn_mfma_f32_16x16x32_bf16(pfrag, onesf, lacc, 0, 0, 0);
        }

        if (s == 0 && q4 == 0) {
            lacc[0] = 1.0f;
            oacc[0] = bs2f(vtb[lr][0]);
        }
        unsigned short* ob = (unsigned short*)o + (size_t)(b * LL + r0) * DD + hh * 16 + lr;
        #pragma unroll
        for (int reg = 0; reg < 4; ++reg) {
            float ov = oacc[reg] / lacc[reg];
            ob[(size_t)(q4 * 4 + reg) * DD] = f2bs(ov);
        }
    }
}

// ---------------- final projection [64,49152] x [49152,128] ----------------
__global__ __launch_bounds__(256) void out_init_kernel(
    const float* __restrict__ bp, float* __restrict__ out)
{
    int t = blockIdx.x * 256 + threadIdx.x;   // 8192
    out[t] = bp[t & (COUT - 1)];
}

// v4: kc on blockIdx.x, mq on blockIdx.y -> the 4 mq-blocks sharing a kc chunk are
// 96 apart (96%8==0 -> same XCD -> Wp chunk served from L2, not HBM, 3 of 4 times).
__global__ __launch_bounds__(256) void final_gemm_kernel(
    const float* __restrict__ xm, const float* __restrict__ Wp,
    float* __restrict__ out)
{
    int kc = blockIdx.x;        // 0..95 -> k chunk of 512
    int mq = blockIdx.y;        // 0..3 -> rows mq*16..+15
    __shared__ float xs[16][520];
    int k0 = kc * 512;
    #pragma unroll
    for (int p = 0; p < 8; ++p) {
        int id = threadIdx.x + p * 256;   // 0..2047 float4s
        int r = id >> 7;
        int c = (id & 127) << 2;
        *(float4*)&xs[r][c] = *(const float4*)(xm + (size_t)(mq * 16 + r) * KP + k0 + c);
    }
    __syncthreads();

    int w = threadIdx.x >> 6, lane = threadIdx.x & 63;
    float acc[16][2];
    #pragma unroll
    for (int r = 0; r < 16; ++r) { acc[r][0] = 0.f; acc[r][1] = 0.f; }

    const float* wbase = Wp + (size_t)(k0 + w * 128) * COUT + 2 * lane;
    for (int ks = 0; ks < 128; ks += 4) {
        float2 wv0 = *(const float2*)(wbase + (size_t)(ks + 0) * COUT);
        float2 wv1 = *(const float2*)(wbase + (size_t)(ks + 1) * COUT);
        float2 wv2 = *(const float2*)(wbase + (size_t)(ks + 2) * COUT);
        float2 wv3 = *(const float2*)(wbase + (size_t)(ks + 3) * COUT);
        #pragma unroll
        for (int r = 0; r < 16; ++r) {
            float4 xv = *(const float4*)&xs[r][w * 128 + ks];
            acc[r][0] = fmaf(xv.x, wv0.x, acc[r][0]);
            acc[r][1] = fmaf(xv.x, wv0.y, acc[r][1]);
            acc[r][0] = fmaf(xv.y, wv1.x, acc[r][0]);
            acc[r][1] = fmaf(xv.y, wv1.y, acc[r][1]);
            acc[r][0] = fmaf(xv.z, wv2.x, acc[r][0]);
            acc[r][1] = fmaf(xv.z, wv2.y, acc[r][1]);
            acc[r][0] = fmaf(xv.w, wv3.x, acc[r][0]);
            acc[r][1] = fmaf(xv.w, wv3.y, acc[r][1]);
        }
    }

    // cross-wave reduce via LDS (xs reused: need 8192 floats, have 8320)
    float* fp = (float*)xs;
    __syncthreads();
    #pragma unroll
    for (int r = 0; r < 16; ++r)
        *(float2*)&fp[w * 2048 + r * 128 + 2 * lane] = make_float2(acc[r][0], acc[r][1]);
    __syncthreads();
    int j0 = threadIdx.x * 8;
    #pragma unroll
    for (int g = 0; g < 2; ++g) {
        int j = j0 + g * 4;
        float4 s0 = *(const float4*)&fp[j];
        float4 s1 = *(const float4*)&fp[2048 + j];
        float4 s2 = *(const float4*)&fp[4096 + j];
        float4 s3 = *(const float4*)&fp[6144 + j];
        float4 sm = make_float4((s0.x + s1.x) + (s2.x + s3.x),
                                (s0.y + s1.y) + (s2.y + s3.y),
                                (s0.z + s1.z) + (s2.z + s3.z),
                                (s0.w + s1.w) + (s2.w + s3.w));
        int r = j >> 7, c = j & 127;
        float* op = out + (size_t)(mq * 16 + r) * COUT + c;
        atomicAdd(op + 0, sm.x);
        atomicAdd(op + 1, sm.y);
        atomicAdd(op + 2, sm.z);
        atomicAdd(op + 3, sm.w);
    }
}

// ---------------- launch ----------------
extern "C" void kernel_launch(void* const* d_in, const int* in_sizes, int n_in,
                              void* d_out, int out_size, void* d_ws, size_t ws_size,
                              hipStream_t stream)
{
    const int*   x_enc = (const int*)  d_in[0];
    const float* emb   = (const float*)d_in[1];
    const float* pos1  = (const float*)d_in[2];
    const float* pos2  = (const float*)d_in[3];
    const float* ln1_g = (const float*)d_in[4];
    const float* ln1_b = (const float*)d_in[5];
    const float* Wqk   = (const float*)d_in[6];
    const float* Wv    = (const float*)d_in[7];
    const float* Wo    = (const float*)d_in[8];
    const float* bo    = (const float*)d_in[9];
    const float* ln2_g = (const float*)d_in[10];
    const float* ln2_b = (const float*)d_in[11];
    const float* W1    = (const float*)d_in[12];
    const float* b1    = (const float*)d_in[13];
    const float* W2    = (const float*)d_in[14];
    const float* b2    = (const float*)d_in[15];
    const float* lnf_g = (const float*)d_in[16];
    const float* lnf_b = (const float*)d_in[17];
    const float* Wp    = (const float*)d_in[18];
    const float* bp    = (const float*)d_in[19];
    float* out = (float*)d_out;

    // workspace layout; SZ = 3,145,728 elements
    const size_t SZ = (size_t)MROWS * DD;
    float* ws_f = (float*)d_ws;
    float* x1 = ws_f;                    // fp32 [M,128]
    float* x2 = ws_f + SZ;               // fp32 [M,128]
    float* R  = ws_f + 2 * SZ;           // 2*SZ floats shared region
    __hip_bfloat16* qkv_bf = (__hip_bfloat16*)R;   // bf16 [M,256] (lifetime: qkv-gemm..attn)
    __hip_bfloat16* hff = (__hip_bfloat16*)R;      // bf16 [M,512] (lifetime: ff1..ff2)
    float* hfin = R;                     // fp32 [M,128]  (final LN out)
    __hip_bfloat16* h_bf = (__hip_bfloat16*)(ws_f + 4 * SZ);  // bf16 [M,128]
    __hip_bfloat16* o_bf = h_bf + SZ;                          // bf16 [M,128]
    __hip_bfloat16* wqvT = o_bf + SZ;    // 6 * [256,128]
    __hip_bfloat16* woT  = wqvT + 6 * 32768;         // 6 * [128,128]
    __hip_bfloat16* w1T  = woT  + 6 * 16384;         // 6 * [512,128]
    __hip_bfloat16* w2T  = w1T  + 6 * 65536;         // 6 * [128,512]

    castT_kernel<<<dim3(4, 4, 6),  dim3(256), 0, stream>>>(Wqk, wqvT,         128, 128, 16384, 32768);
    castT_kernel<<<dim3(4, 4, 6),  dim3(256), 0, stream>>>(Wv,  wqvT + 16384, 128, 128, 16384, 32768);
    castT_kernel<<<dim3(4, 4, 6),  dim3(256), 0, stream>>>(Wo,  woT,          128, 128, 16384, 16384);
    castT_kernel<<<dim3(4, 16, 6), dim3(256), 0, stream>>>(W1,  w1T,          128, 512, 65536, 65536);
    castT_kernel<<<dim3(16, 4, 6), dim3(256), 0, stream>>>(W2,  w2T,          512, 128, 65536, 65536);

    embed_kernel<<<dim3(MROWS * 32 / 256), dim3(256), 0, stream>>>(x_enc, emb, pos1, pos2, x1, x2);
    // layer-0 ln1 (subsequent ln1/ln2 are fused into ff2/wo epilogues)
    ln_kernel<<<dim3(MROWS / 4), dim3(256), 0, stream>>>(x2, ln1_g, ln1_b, h_bf);

    for (int d = 0; d < DEPTH; ++d) {
        const float* bod = bo + d * DD;
        const float* l2g = ln2_g + d * DD;
        const float* l2b = ln2_b + d * DD;
        const float* b1d = b1 + d * FFD;
        const float* b2d = b2 + d * DD;
        const __hip_bfloat16* wqv_d = wqvT + (size_t)d * 32768;
        const __hip_bfloat16* wo_d  = woT  + (size_t)d * 16384;
        const __hip_bfloat16* w1_d  = w1T  + (size_t)d * 65536;
        const __hip_bfloat16* w2_d  = w2T  + (size_t)d * 65536;

        gemm_bf16<128, 256, false, false, false, true, false>
            <<<dim3(2, MROWS / 64), dim3(256), 0, stream>>>(
                h_bf, wqv_d, nullptr, nullptr, qkv_bf, nullptr, nullptr, nullptr);
        attn_kernel<<<dim3(BB * HH * 2), dim3(256), 0, stream>>>(qkv_bf, o_bf);
        // x1 += o@Wo + bo ; h_bf = LN2(x1)   (fused)
        gemm_bf16<128, 128, true, true, false, false, true>
            <<<dim3(1, MROWS / 64), dim3(256), 0, stream>>>(
                o_bf, wo_d, bod, x1, x1, l2g, l2b, h_bf);
        gemm_bf16<128, 512, true, false, true, true, false>
            <<<dim3(4, MROWS / 64), dim3(256), 0, stream>>>(
                h_bf, w1_d, b1d, nullptr, hff, nullptr, nullptr, nullptr);
        if (d < DEPTH - 1) {
            // x2 += hff@W2 + b2 ; h_bf = LN1[d+1](x2)   (fused)
            gemm_bf16<512, 128, true, true, false, false, true>
                <<<dim3(1, MROWS / 64), dim3(256), 0, stream>>>(
                    hff, w2_d, b2d, x2, x2, ln1_g + (d + 1) * DD, ln1_b + (d + 1) * DD, h_bf);
        } else {
            gemm_bf16<512, 128, true, true, false, false, false>
                <<<dim3(1, MROWS / 64), dim3(256), 0, stream>>>(
                    hff, w2_d, b2d, x2, x2, nullptr, nullptr, nullptr);
        }
    }

    avgln_kernel<<<dim3(MROWS / 4), dim3(256), 0, stream>>>(x1, x2, lnf_g, lnf_b, hfin);
    out_init_kernel<<<dim3(32), dim3(256), 0, stream>>>(bp, out);
    final_gemm_kernel<<<dim3(96, 4), dim3(256), 0, stream>>>(hfin, Wp, out);
}

// Round 10
// 680.928 us; speedup vs baseline: 1.0567x; 1.0423x over previous
//
#include <hip/hip_runtime.h>
#include <hip/hip_bf16.h>
#include <math.h>

#define BB 64
#define LL 384
#define DD 128
#define HH 8
#define DHH 16
#define DEPTH 6
#define FFD 512
#define MROWS (BB*LL)      // 24576
#define COUT 128
#define KP (LL*DD)         // 49152
#define KSPLIT 96
#define KCHUNK 512

typedef short bf16x8 __attribute__((ext_vector_type(8)));
typedef float f32x4 __attribute__((ext_vector_type(4)));

__device__ __forceinline__ unsigned short f2bs(float x) {
    __hip_bfloat16 h = __float2bfloat16(x);
    return *reinterpret_cast<unsigned short*>(&h);
}
__device__ __forceinline__ float bs2f(unsigned short u) {
    unsigned int v = ((unsigned int)u) << 16;
    return __uint_as_float(v);
}

// ---------------- embed + axial pos ----------------
__global__ __launch_bounds__(256) void embed_kernel(
    const int* __restrict__ x_enc, const float* __restrict__ emb,
    const float* __restrict__ pos1, const float* __restrict__ pos2,
    float* __restrict__ x1, float* __restrict__ x2)
{
    int t = blockIdx.x * 256 + threadIdx.x;      // over MROWS * 32 float4
    int row = t >> 5;
    int c4 = t & 31;
    int l = row % LL;
    int tok = x_enc[row];
    float4 a = ((const float4*)(emb + (size_t)tok * DD))[c4];
    float4 b = ((const float4*)(pos1 + (l / 25) * DD))[c4];
    float4 c = ((const float4*)(pos2 + (l % 25) * DD))[c4];
    float4 r = make_float4(a.x + b.x + c.x, a.y + b.y + c.y,
                           a.z + b.z + c.z, a.w + b.w + c.w);
    ((float4*)x1)[t] = r;
    ((float4*)x2)[t] = r;
}

// ---------------- weight cast + transpose: W[K,N] fp32 -> Wt[N,K] bf16 ----------------
__global__ __launch_bounds__(256) void castT_kernel(
    const float* __restrict__ src, __hip_bfloat16* __restrict__ dst, int K, int N,
    long sstride, long dstride)
{
    __shared__ float tile[32][33];
    int kb = blockIdx.x * 32, nb = blockIdx.y * 32;
    int tx = threadIdx.x & 31, ty = threadIdx.x >> 5;   // ty 0..7
    const float* s = src + (size_t)blockIdx.z * sstride;
    __hip_bfloat16* d = dst + (size_t)blockIdx.z * dstride;
    #pragma unroll
    for (int r = 0; r < 32; r += 8)
        tile[r + ty][tx] = s[(size_t)(kb + r + ty) * N + nb + tx];
    __syncthreads();
    #pragma unroll
    for (int r = 0; r < 32; r += 8)
        d[(size_t)(nb + r + ty) * K + kb + tx] = __float2bfloat16(tile[tx][r + ty]);
}

// ---------------- LayerNorm (wave per row) -> bf16 out (layer-0 ln1 only) ----------------
__global__ __launch_bounds__(256) void ln_kernel(
    const float* __restrict__ x, const float* __restrict__ g,
    const float* __restrict__ b, __hip_bfloat16* __restrict__ y)
{
    int wave = threadIdx.x >> 6;
    int lane = threadIdx.x & 63;
    int row = blockIdx.x * 4 + wave;
    float2 v = ((const float2*)(x + (size_t)row * DD))[lane];
    float2 gg = ((const float2*)g)[lane];
    float2 bb = ((const float2*)b)[lane];
    float s = v.x + v.y;
    float sq = v.x * v.x + v.y * v.y;
    #pragma unroll
    for (int off = 32; off > 0; off >>= 1) {
        s += __shfl_down(s, off, 64);
        sq += __shfl_down(sq, off, 64);
    }
    s = __shfl(s, 0, 64);
    sq = __shfl(sq, 0, 64);
    float mean = s * (1.0f / DD);
    float var = sq * (1.0f / DD) - mean * mean;
    float rstd = rsqrtf(var + 1e-5f);
    __hip_bfloat16* yp = y + (size_t)row * DD + lane * 2;
    yp[0] = __float2bfloat16((v.x - mean) * rstd * gg.x + bb.x);
    yp[1] = __float2bfloat16((v.y - mean) * rstd * gg.y + bb.y);
}

// avg + LN -> bf16 out (input of the final MFMA projection)
__global__ __launch_bounds__(256) void avgln_kernel(
    const float* __restrict__ xa, const float* __restrict__ xb,
    const float* __restrict__ g, const float* __restrict__ b,
    __hip_bfloat16* __restrict__ y)
{
    int wave = threadIdx.x >> 6;
    int lane = threadIdx.x & 63;
    int row = blockIdx.x * 4 + wave;
    float2 va = ((const float2*)(xa + (size_t)row * DD))[lane];
    float2 vb = ((const float2*)(xb + (size_t)row * DD))[lane];
    float2 v = make_float2((va.x + vb.x) * 0.5f, (va.y + vb.y) * 0.5f);
    float2 gg = ((const float2*)g)[lane];
    float2 bb = ((const float2*)b)[lane];
    float s = v.x + v.y;
    float sq = v.x * v.x + v.y * v.y;
    #pragma unroll
    for (int off = 32; off > 0; off >>= 1) {
        s += __shfl_down(s, off, 64);
        sq += __shfl_down(sq, off, 64);
    }
    s = __shfl(s, 0, 64);
    sq = __shfl(sq, 0, 64);
    float mean = s * (1.0f / DD);
    float var = sq * (1.0f / DD) - mean * mean;
    float rstd = rsqrtf(var + 1e-5f);
    __hip_bfloat16* yp = y + (size_t)row * DD + lane * 2;
    yp[0] = __float2bfloat16((v.x - mean) * rstd * gg.x + bb.x);
    yp[1] = __float2bfloat16((v.y - mean) * rstd * gg.y + bb.y);
}

// ---------------- bf16 MFMA GEMM (optional fused row-LayerNorm epilogue) ----------------
__device__ __forceinline__ float gelu_exact(float x) {
    return 0.5f * x * (1.0f + erff(x * 0.70710678118654752f));
}

template<int K, int N, bool BIAS, bool RES, bool GELU, bool OBF, bool LNOUT>
__global__ __launch_bounds__(256) void gemm_bf16(
    const __hip_bfloat16* __restrict__ A, const __hip_bfloat16* __restrict__ Bt,
    const float* __restrict__ bias, const float* __restrict__ Rsrc,
    void* __restrict__ Cdst,
    const float* __restrict__ lng, const float* __restrict__ lnb,
    __hip_bfloat16* __restrict__ lnout)
{
    __shared__ unsigned short As[64 * 128];    // 16 KB
    __shared__ unsigned short Bs[128 * 128];   // 32 KB
    int tid = threadIdx.x;
    int l = tid & 63, w = tid >> 6;
    int wr = w >> 1, wc = w & 1;
    int lr = l & 15, q = l >> 4;
    int m0 = blockIdx.y * 64;
    int n0 = blockIdx.x * 128;

    f32x4 acc[2][4];
    #pragma unroll
    for (int mt = 0; mt < 2; ++mt)
        #pragma unroll
        for (int nt = 0; nt < 4; ++nt) acc[mt][nt] = (f32x4){0.f, 0.f, 0.f, 0.f};

    for (int kt = 0; kt < K; kt += 128) {
        if (kt) __syncthreads();
        #pragma unroll
        for (int p = 0; p < 4; ++p) {
            int n = p * 256 + tid;
            int r = n >> 4;
            int c = (n & 15) ^ (r & 7);
            uint4 dv = *(const uint4*)(A + (size_t)(m0 + r) * K + kt + c * 8);
            *(uint4*)&As[n * 8] = dv;
        }
        #pragma unroll
        for (int p = 0; p < 8; ++p) {
            int n = p * 256 + tid;
            int r = n >> 4;
            int c = (n & 15) ^ (r & 7);
            uint4 dv = *(const uint4*)(Bt + (size_t)(n0 + r) * K + kt + c * 8);
            *(uint4*)&Bs[n * 8] = dv;
        }
        __syncthreads();

        #pragma unroll
        for (int kk = 0; kk < 4; ++kk) {
            bf16x8 afr[2], bfr[4];
            #pragma unroll
            for (int mt = 0; mt < 2; ++mt) {
                int rA = wr * 32 + mt * 16 + lr;
                int cc = (kk * 4 + q) ^ (rA & 7);
                afr[mt] = *(const bf16x8*)&As[(rA * 16 + cc) * 8];
            }
            #pragma unroll
            for (int nt = 0; nt < 4; ++nt) {
                int rB = wc * 64 + nt * 16 + lr;
                int cc = (kk * 4 + q) ^ (rB & 7);
                bfr[nt] = *(const bf16x8*)&Bs[(rB * 16 + cc) * 8];
            }
            #pragma unroll
            for (int mt = 0; mt < 2; ++mt)
                #pragma unroll
                for (int nt = 0; nt < 4; ++nt)
                    acc[mt][nt] = __builtin_amdgcn_mfma_f32_16x16x32_bf16(
                        afr[mt], bfr[nt], acc[mt][nt], 0, 0, 0);
        }
    }

    if (!LNOUT) {
        #pragma unroll
        for (int mt = 0; mt < 2; ++mt) {
            #pragma unroll
            for (int nt = 0; nt < 4; ++nt) {
                int col = n0 + wc * 64 + nt * 16 + lr;
                float bv = BIAS ? bias[col] : 0.f;
                #pragma unroll
                for (int r = 0; r < 4; ++r) {
                    int row = m0 + wr * 32 + mt * 16 + q * 4 + r;
                    float val = acc[mt][nt][r] + bv;
                    if (GELU) val = gelu_exact(val);
                    if (RES) val += Rsrc[(size_t)row * N + col];
                    if (OBF) ((__hip_bfloat16*)Cdst)[(size_t)row * N + col] = __float2bfloat16(val);
                    else     ((float*)Cdst)[(size_t)row * N + col] = val;
                }
            }
        }
    } else {
        float* fp = (float*)Bs;    // 64 x 128 fp32 tile = 32 KB (Bs reused)
        __syncthreads();           // all waves done reading As/Bs
        #pragma unroll
        for (int mt = 0; mt < 2; ++mt) {
            #pragma unroll
            for (int nt = 0; nt < 4; ++nt) {
                int col = wc * 64 + nt * 16 + lr;
                float bv = BIAS ? bias[col] : 0.f;
                #pragma unroll
                for (int r = 0; r < 4; ++r) {
                    int rowL = wr * 32 + mt * 16 + q * 4 + r;
                    float val = acc[mt][nt][r] + bv;
                    if (RES) val += Rsrc[(size_t)(m0 + rowL) * N + col];
                    fp[rowL * 128 + col] = val;
                }
            }
        }
        __syncthreads();
        int rl = tid >> 2, sub = tid & 3;          // 64 rows x 4 col-groups
        float s = 0.f, sq = 0.f;
        #pragma unroll
        for (int c4 = 0; c4 < 8; ++c4) {
            float4 v = *(const float4*)&fp[rl * 128 + sub * 32 + c4 * 4];
            s  += (v.x + v.y) + (v.z + v.w);
            sq += (v.x * v.x + v.y * v.y) + (v.z * v.z + v.w * v.w);
        }
        s  += __shfl_xor(s, 1);  s  += __shfl_xor(s, 2);
        sq += __shfl_xor(sq, 1); sq += __shfl_xor(sq, 2);
        float mean = s * (1.0f / 128.0f);
        float var  = sq * (1.0f / 128.0f) - mean * mean;
        float rstd = rsqrtf(var + 1e-5f);
        int rowG = m0 + rl;
        #pragma unroll
        for (int c4 = 0; c4 < 8; ++c4) {
            int col = sub * 32 + c4 * 4;
            float4 v  = *(const float4*)&fp[rl * 128 + col];
            float4 g4 = *(const float4*)(lng + col);
            float4 b4 = *(const float4*)(lnb + col);
            *(float4*)((float*)Cdst + (size_t)rowG * 128 + col) = v;   // residual stream
            unsigned short pk[4];
            pk[0] = f2bs((v.x - mean) * rstd * g4.x + b4.x);
            pk[1] = f2bs((v.y - mean) * rstd * g4.y + b4.y);
            pk[2] = f2bs((v.z - mean) * rstd * g4.z + b4.z);
            pk[3] = f2bs((v.w - mean) * rstd * g4.w + b4.w);
            *(ushort4*)((unsigned short*)lnout + (size_t)rowG * 128 + col) = *(ushort4*)&pk[0];
        }
    }
}

// ---------------- attention: MFMA flash-style, bf16 qkv input ----------------
__global__ __launch_bounds__(256) void attn_kernel(
    const __hip_bfloat16* __restrict__ qkv, __hip_bfloat16* __restrict__ o)
{
    int z  = blockIdx.x >> 9;
    int bh = blockIdx.x & 511;
    int b = bh >> 3, hh = bh & 7;
    const unsigned short* base = (const unsigned short*)qkv + (size_t)b * LL * 256 + hh * DHH;

    __shared__ unsigned short knb[LL + 2][24];   // qhat/khat bf16; cols 16..23 zeroed
    __shared__ unsigned short vtb[16][LL + 24];  // V^T bf16; cols 384..407 zeroed
    __shared__ float cq[LL];                     // 0.25*|q|
    __shared__ unsigned short ptile[4][16][40];  // per-wave P tile; cols 16..31 zeroed

    int t = threadIdx.x;
    for (int r = t; r < LL; r += 256) {
        const unsigned short* qp = base + (size_t)r * 256;
        unsigned short qs[16], vs16[16];
        *(uint4*)&qs[0]  = *(const uint4*)(qp);
        *(uint4*)&qs[8]  = *(const uint4*)(qp + 8);
        *(uint4*)&vs16[0] = *(const uint4*)(qp + 128);
        *(uint4*)&vs16[8] = *(const uint4*)(qp + 136);
        float q[16];
        #pragma unroll
        for (int d = 0; d < 16; ++d) q[d] = bs2f(qs[d]);
        float nrm = 0.f;
        #pragma unroll
        for (int d = 0; d < 16; ++d) nrm = fmaf(q[d], q[d], nrm);
        float qn = sqrtf(nrm);
        float inv = 1.0f / fmaxf(qn, 1e-12f);
        cq[r] = 0.25f * qn;
        unsigned short kb[16];
        #pragma unroll
        for (int d = 0; d < 16; ++d) kb[d] = f2bs(q[d] * inv);
        *(uint4*)&knb[r][0] = *(uint4*)&kb[0];
        *(uint4*)&knb[r][8] = *(uint4*)&kb[8];
        *(uint4*)&knb[r][16] = make_uint4(0u, 0u, 0u, 0u);
        #pragma unroll
        for (int d = 0; d < 16; ++d) vtb[d][r] = vs16[d];
    }
    if (t < 16) {
        #pragma unroll
        for (int c = 0; c < 24; ++c) vtb[t][LL + c] = 0;
    }

    int w = t >> 6, l = t & 63;
    int lr = l & 15, q4 = l >> 4;
    *(uint2*)&ptile[w][lr][16 + q4 * 4] = make_uint2(0u, 0u);
    __syncthreads();

    bf16x8 zfrag = {0, 0, 0, 0, 0, 0, 0, 0};
    bf16x8 onesf;
    #pragma unroll
    for (int i = 0; i < 8; ++i) onesf[i] = (short)0x3F80;

    int slot = 2 * w + z;
    int strips[3] = { slot, 15 - slot, 16 + slot };
    #pragma unroll
    for (int si = 0; si < 3; ++si) {
        int s = strips[si];
        int r0 = s * 16;
        bf16x8 afrag = *(const bf16x8*)&knb[r0 + lr][(q4 & 1) * 8];
        afrag = (q4 < 2) ? afrag : zfrag;
        float ccv[4];
        #pragma unroll
        for (int reg = 0; reg < 4; ++reg) ccv[reg] = cq[r0 + q4 * 4 + reg];

        f32x4 oacc = (f32x4){0.f, 0.f, 0.f, 0.f};
        f32x4 lacc = (f32x4){0.f, 0.f, 0.f, 0.f};

        for (int jt = 0; jt <= s; ++jt) {
            bf16x8 bfrag = *(const bf16x8*)&knb[jt * 16 + lr][q4 * 8];
            f32x4 sacc = __builtin_amdgcn_mfma_f32_16x16x32_bf16(
                afrag, bfrag, (f32x4){0.f, 0.f, 0.f, 0.f}, 0, 0, 0);
            int colg = jt * 16 + lr;
            #pragma unroll
            for (int reg = 0; reg < 4; ++reg) {
                int rowg = r0 + q4 * 4 + reg;
                float pe = __expf(fmaf(sacc[reg], ccv[reg], -ccv[reg]));
                pe = (colg < rowg) ? pe : 0.f;
                ptile[w][q4 * 4 + reg][lr] = f2bs(pe);
            }
            asm volatile("s_waitcnt lgkmcnt(0)" ::: "memory");
            bf16x8 pfrag = *(const bf16x8*)&ptile[w][lr][q4 * 8];
            bf16x8 vfrag = *(const bf16x8*)&vtb[lr][jt * 16 + q4 * 8];
            oacc = __builtin_amdgcn_mfma_f32_16x16x32_bf16(pfrag, vfrag, oacc, 0, 0, 0);
            lacc = __builtin_amdgcn_mfma_f32_16x16x32_bf16(pfrag, onesf, lacc, 0, 0, 0);
        }

        if (s == 0 && q4 == 0) {
            lacc[0] = 1.0f;
            oacc[0] = bs2f(vtb[lr][0]);
        }
        unsigned short* ob = (unsigned short*)o + (size_t)(b * LL + r0) * DD + hh * 16 + lr;
        #pragma unroll
        for (int reg = 0; reg < 4; ++reg) {
            float ov = oacc[reg] / lacc[reg];
            ob[(size_t)(q4 * 4 + reg) * DD] = f2bs(ov);
        }
    }
}

// ---------------- final projection: MFMA split-K + reduce ----------------
// A = avgln output [64, 49152] bf16, Bt = WpT [128, 49152] bf16.
// 96 blocks, each computes the 64x128 partial over a 512-wide K chunk; plain
// stores to partials (no atomics), then a reduce kernel adds bias.
__global__ __launch_bounds__(256) void final_mfma_kernel(
    const __hip_bfloat16* __restrict__ A, const __hip_bfloat16* __restrict__ Bt,
    float* __restrict__ partials)
{
    __shared__ unsigned short As[64 * 128];
    __shared__ unsigned short Bs[128 * 128];
    int tid = threadIdx.x;
    int l = tid & 63, w = tid >> 6;
    int wr = w >> 1, wc = w & 1;
    int lr = l & 15, q = l >> 4;
    int kbase = blockIdx.x * KCHUNK;

    f32x4 acc[2][4];
    #pragma unroll
    for (int mt = 0; mt < 2; ++mt)
        #pragma unroll
        for (int nt = 0; nt < 4; ++nt) acc[mt][nt] = (f32x4){0.f, 0.f, 0.f, 0.f};

    for (int kt = 0; kt < KCHUNK; kt += 128) {
        if (kt) __syncthreads();
        #pragma unroll
        for (int p = 0; p < 4; ++p) {
            int n = p * 256 + tid;
            int r = n >> 4;
            int c = (n & 15) ^ (r & 7);
            uint4 dv = *(const uint4*)(A + (size_t)r * KP + kbase + kt + c * 8);
            *(uint4*)&As[n * 8] = dv;
        }
        #pragma unroll
        for (int p = 0; p < 8; ++p) {
            int n = p * 256 + tid;
            int r = n >> 4;
            int c = (n & 15) ^ (r & 7);
            uint4 dv = *(const uint4*)(Bt + (size_t)r * KP + kbase + kt + c * 8);
            *(uint4*)&Bs[n * 8] = dv;
        }
        __syncthreads();

        #pragma unroll
        for (int kk = 0; kk < 4; ++kk) {
            bf16x8 afr[2], bfr[4];
            #pragma unroll
            for (int mt = 0; mt < 2; ++mt) {
                int rA = wr * 32 + mt * 16 + lr;
                int cc = (kk * 4 + q) ^ (rA & 7);
                afr[mt] = *(const bf16x8*)&As[(rA * 16 + cc) * 8];
            }
            #pragma unroll
            for (int nt = 0; nt < 4; ++nt) {
                int rB = wc * 64 + nt * 16 + lr;
                int cc = (kk * 4 + q) ^ (rB & 7);
                bfr[nt] = *(const bf16x8*)&Bs[(rB * 16 + cc) * 8];
            }
            #pragma unroll
            for (int mt = 0; mt < 2; ++mt)
                #pragma unroll
                for (int nt = 0; nt < 4; ++nt)
                    acc[mt][nt] = __builtin_amdgcn_mfma_f32_16x16x32_bf16(
                        afr[mt], bfr[nt], acc[mt][nt], 0, 0, 0);
        }
    }

    float* dst = partials + (size_t)blockIdx.x * (64 * 128);
    #pragma unroll
    for (int mt = 0; mt < 2; ++mt) {
        #pragma unroll
        for (int nt = 0; nt < 4; ++nt) {
            int col = wc * 64 + nt * 16 + lr;
            #pragma unroll
            for (int r = 0; r < 4; ++r) {
                int row = wr * 32 + mt * 16 + q * 4 + r;
                dst[row * 128 + col] = acc[mt][nt][r];
            }
        }
    }
}

__global__ __launch_bounds__(256) void final_reduce_kernel(
    const float* __restrict__ partials, const float* __restrict__ bp,
    float* __restrict__ out)
{
    int j = blockIdx.x * 256 + threadIdx.x;   // 0..8191
    float s = bp[j & (COUT - 1)];
    #pragma unroll 8
    for (int p = 0; p < KSPLIT; ++p)
        s += partials[(size_t)p * 8192 + j];
    out[j] = s;
}

// ---------------- launch ----------------
extern "C" void kernel_launch(void* const* d_in, const int* in_sizes, int n_in,
                              void* d_out, int out_size, void* d_ws, size_t ws_size,
                              hipStream_t stream)
{
    const int*   x_enc = (const int*)  d_in[0];
    const float* emb   = (const float*)d_in[1];
    const float* pos1  = (const float*)d_in[2];
    const float* pos2  = (const float*)d_in[3];
    const float* ln1_g = (const float*)d_in[4];
    const float* ln1_b = (const float*)d_in[5];
    const float* Wqk   = (const float*)d_in[6];
    const float* Wv    = (const float*)d_in[7];
    const float* Wo    = (const float*)d_in[8];
    const float* bo    = (const float*)d_in[9];
    const float* ln2_g = (const float*)d_in[10];
    const float* ln2_b = (const float*)d_in[11];
    const float* W1    = (const float*)d_in[12];
    const float* b1    = (const float*)d_in[13];
    const float* W2    = (const float*)d_in[14];
    const float* b2    = (const float*)d_in[15];
    const float* lnf_g = (const float*)d_in[16];
    const float* lnf_b = (const float*)d_in[17];
    const float* Wp    = (const float*)d_in[18];
    const float* bp    = (const float*)d_in[19];
    float* out = (float*)d_out;

    // workspace layout; SZ = 3,145,728 elements
    const size_t SZ = (size_t)MROWS * DD;
    float* ws_f = (float*)d_ws;
    float* x1 = ws_f;                    // fp32 [M,128]
    float* x2 = ws_f + SZ;               // fp32 [M,128]
    float* R  = ws_f + 2 * SZ;           // 2*SZ floats shared region
    __hip_bfloat16* qkv_bf = (__hip_bfloat16*)R;   // bf16 [M,256] (lifetime: qkv-gemm..attn)
    __hip_bfloat16* hff = (__hip_bfloat16*)R;      // bf16 [M,512] (lifetime: ff1..ff2)
    __hip_bfloat16* h_bf = (__hip_bfloat16*)(ws_f + 4 * SZ);  // bf16 [M,128]
    __hip_bfloat16* o_bf = h_bf + SZ;                          // bf16 [M,128]
    __hip_bfloat16* wqvT = o_bf + SZ;    // 6 * [256,128]
    __hip_bfloat16* woT  = wqvT + 6 * 32768;         // 6 * [128,128]
    __hip_bfloat16* w1T  = woT  + 6 * 16384;         // 6 * [512,128]
    __hip_bfloat16* w2T  = w1T  + 6 * 65536;         // 6 * [128,512]
    __hip_bfloat16* WpT  = w2T  + 6 * 65536;         // [128, 49152] bf16
    float* partials = (float*)(WpT + (size_t)COUT * KP);   // [96][8192] fp32

    castT_kernel<<<dim3(4, 4, 6),  dim3(256), 0, stream>>>(Wqk, wqvT,         128, 128, 16384, 32768);
    castT_kernel<<<dim3(4, 4, 6),  dim3(256), 0, stream>>>(Wv,  wqvT + 16384, 128, 128, 16384, 32768);
    castT_kernel<<<dim3(4, 4, 6),  dim3(256), 0, stream>>>(Wo,  woT,          128, 128, 16384, 16384);
    castT_kernel<<<dim3(4, 16, 6), dim3(256), 0, stream>>>(W1,  w1T,          128, 512, 65536, 65536);
    castT_kernel<<<dim3(16, 4, 6), dim3(256), 0, stream>>>(W2,  w2T,          512, 128, 65536, 65536);
    castT_kernel<<<dim3(KP / 32, 4, 1), dim3(256), 0, stream>>>(Wp, WpT, KP, 128, 0, 0);

    embed_kernel<<<dim3(MROWS * 32 / 256), dim3(256), 0, stream>>>(x_enc, emb, pos1, pos2, x1, x2);
    // layer-0 ln1 (subsequent ln1/ln2 are fused into ff2/wo epilogues)
    ln_kernel<<<dim3(MROWS / 4), dim3(256), 0, stream>>>(x2, ln1_g, ln1_b, h_bf);

    for (int d = 0; d < DEPTH; ++d) {
        const float* bod = bo + d * DD;
        const float* l2g = ln2_g + d * DD;
        const float* l2b = ln2_b + d * DD;
        const float* b1d = b1 + d * FFD;
        const float* b2d = b2 + d * DD;
        const __hip_bfloat16* wqv_d = wqvT + (size_t)d * 32768;
        const __hip_bfloat16* wo_d  = woT  + (size_t)d * 16384;
        const __hip_bfloat16* w1_d  = w1T  + (size_t)d * 65536;
        const __hip_bfloat16* w2_d  = w2T  + (size_t)d * 65536;

        gemm_bf16<128, 256, false, false, false, true, false>
            <<<dim3(2, MROWS / 64), dim3(256), 0, stream>>>(
                h_bf, wqv_d, nullptr, nullptr, qkv_bf, nullptr, nullptr, nullptr);
        attn_kernel<<<dim3(BB * HH * 2), dim3(256), 0, stream>>>(qkv_bf, o_bf);
        // x1 += o@Wo + bo ; h_bf = LN2(x1)   (fused)
        gemm_bf16<128, 128, true, true, false, false, true>
            <<<dim3(1, MROWS / 64), dim3(256), 0, stream>>>(
                o_bf, wo_d, bod, x1, x1, l2g, l2b, h_bf);
        gemm_bf16<128, 512, true, false, true, true, false>
            <<<dim3(4, MROWS / 64), dim3(256), 0, stream>>>(
                h_bf, w1_d, b1d, nullptr, hff, nullptr, nullptr, nullptr);
        if (d < DEPTH - 1) {
            // x2 += hff@W2 + b2 ; h_bf = LN1[d+1](x2)   (fused)
            gemm_bf16<512, 128, true, true, false, false, true>
                <<<dim3(1, MROWS / 64), dim3(256), 0, stream>>>(
                    hff, w2_d, b2d, x2, x2, ln1_g + (d + 1) * DD, ln1_b + (d + 1) * DD, h_bf);
        } else {
            gemm_bf16<512, 128, true, true, false, false, false>
                <<<dim3(1, MROWS / 64), dim3(256), 0, stream>>>(
                    hff, w2_d, b2d, x2, x2, nullptr, nullptr, nullptr);
        }
    }

    // final LN -> bf16, then MFMA split-K projection + reduce
    avgln_kernel<<<dim3(MROWS / 4), dim3(256), 0, stream>>>(x1, x2, lnf_g, lnf_b, h_bf);
    final_mfma_kernel<<<dim3(KSPLIT), dim3(256), 0, stream>>>(h_bf, WpT, partials);
    final_reduce_kernel<<<dim3(32), dim3(256), 0, stream>>>(partials, bp, out);
}

// Round 11
// 670.415 us; speedup vs baseline: 1.0733x; 1.0157x over previous
//
#include <hip/hip_runtime.h>
#include <hip/hip_bf16.h>
#include <math.h>

#define BB 64
#define LL 384
#define DD 128
#define HH 8
#define DHH 16
#define DEPTH 6
#define FFD 512
#define MROWS (BB*LL)      // 24576
#define COUT 128
#define KP (LL*DD)         // 49152
#define KSPLIT 96
#define KCHUNK 512

typedef short bf16x8 __attribute__((ext_vector_type(8)));
typedef float f32x4 __attribute__((ext_vector_type(4)));

__device__ __forceinline__ unsigned short f2bs(float x) {
    __hip_bfloat16 h = __float2bfloat16(x);
    return *reinterpret_cast<unsigned short*>(&h);
}
__device__ __forceinline__ float bs2f(unsigned short u) {
    unsigned int v = ((unsigned int)u) << 16;
    return __uint_as_float(v);
}

// ---------------- embed + axial pos ----------------
__global__ __launch_bounds__(256) void embed_kernel(
    const int* __restrict__ x_enc, const float* __restrict__ emb,
    const float* __restrict__ pos1, const float* __restrict__ pos2,
    float* __restrict__ x1, float* __restrict__ x2)
{
    int t = blockIdx.x * 256 + threadIdx.x;      // over MROWS * 32 float4
    int row = t >> 5;
    int c4 = t & 31;
    int l = row % LL;
    int tok = x_enc[row];
    float4 a = ((const float4*)(emb + (size_t)tok * DD))[c4];
    float4 b = ((const float4*)(pos1 + (l / 25) * DD))[c4];
    float4 c = ((const float4*)(pos2 + (l % 25) * DD))[c4];
    float4 r = make_float4(a.x + b.x + c.x, a.y + b.y + c.y,
                           a.z + b.z + c.z, a.w + b.w + c.w);
    ((float4*)x1)[t] = r;
    ((float4*)x2)[t] = r;
}

// ---------------- weight cast + transpose: W[K,N] fp32 -> Wt[N,K] bf16 ----------------
__global__ __launch_bounds__(256) void castT_kernel(
    const float* __restrict__ src, __hip_bfloat16* __restrict__ dst, int K, int N,
    long sstride, long dstride)
{
    __shared__ float tile[32][33];
    int kb = blockIdx.x * 32, nb = blockIdx.y * 32;
    int tx = threadIdx.x & 31, ty = threadIdx.x >> 5;   // ty 0..7
    const float* s = src + (size_t)blockIdx.z * sstride;
    __hip_bfloat16* d = dst + (size_t)blockIdx.z * dstride;
    #pragma unroll
    for (int r = 0; r < 32; r += 8)
        tile[r + ty][tx] = s[(size_t)(kb + r + ty) * N + nb + tx];
    __syncthreads();
    #pragma unroll
    for (int r = 0; r < 32; r += 8)
        d[(size_t)(nb + r + ty) * K + kb + tx] = __float2bfloat16(tile[tx][r + ty]);
}

// merged cast for the three 128x128 weight families (Wqk, Wv, Wo), z in [0,18)
__global__ __launch_bounds__(256) void castT3_kernel(
    const float* __restrict__ sqk, const float* __restrict__ sv, const float* __restrict__ so,
    __hip_bfloat16* __restrict__ dqk, __hip_bfloat16* __restrict__ dv,
    __hip_bfloat16* __restrict__ dwo)
{
    __shared__ float tile[32][33];
    int which = blockIdx.z / 6;
    int dd = blockIdx.z % 6;
    const float* s = (which == 0 ? sqk : (which == 1 ? sv : so)) + (size_t)dd * 16384;
    __hip_bfloat16* d = (which == 0 ? dqk : (which == 1 ? dv : dwo))
                        + (size_t)dd * (which == 2 ? 16384 : 32768);
    int kb = blockIdx.x * 32, nb = blockIdx.y * 32;
    int tx = threadIdx.x & 31, ty = threadIdx.x >> 5;
    #pragma unroll
    for (int r = 0; r < 32; r += 8)
        tile[r + ty][tx] = s[(size_t)(kb + r + ty) * 128 + nb + tx];
    __syncthreads();
    #pragma unroll
    for (int r = 0; r < 32; r += 8)
        d[(size_t)(nb + r + ty) * 128 + kb + tx] = __float2bfloat16(tile[tx][r + ty]);
}

// ---------------- LayerNorm (wave per row) -> bf16 out (layer-0 ln1 only) ----------------
__global__ __launch_bounds__(256) void ln_kernel(
    const float* __restrict__ x, const float* __restrict__ g,
    const float* __restrict__ b, __hip_bfloat16* __restrict__ y)
{
    int wave = threadIdx.x >> 6;
    int lane = threadIdx.x & 63;
    int row = blockIdx.x * 4 + wave;
    float2 v = ((const float2*)(x + (size_t)row * DD))[lane];
    float2 gg = ((const float2*)g)[lane];
    float2 bb = ((const float2*)b)[lane];
    float s = v.x + v.y;
    float sq = v.x * v.x + v.y * v.y;
    #pragma unroll
    for (int off = 32; off > 0; off >>= 1) {
        s += __shfl_down(s, off, 64);
        sq += __shfl_down(sq, off, 64);
    }
    s = __shfl(s, 0, 64);
    sq = __shfl(sq, 0, 64);
    float mean = s * (1.0f / DD);
    float var = sq * (1.0f / DD) - mean * mean;
    float rstd = rsqrtf(var + 1e-5f);
    __hip_bfloat16* yp = y + (size_t)row * DD + lane * 2;
    yp[0] = __float2bfloat16((v.x - mean) * rstd * gg.x + bb.x);
    yp[1] = __float2bfloat16((v.y - mean) * rstd * gg.y + bb.y);
}

// ---------------- bf16 MFMA GEMM (optional fused LayerNorm / avg-LN epilogue) ----------------
__device__ __forceinline__ float gelu_exact(float x) {
    return 0.5f * x * (1.0f + erff(x * 0.70710678118654752f));
}

// LNOUT: N==128, gridDim.x==1. Writes Cdst (residual fp32) and lnout = LN(row).
// AVGLN (implies LNOUT): LN input = (Rsrc2[row] + val)*0.5 (final avg-LN); Cdst not written.
template<int K, int N, bool BIAS, bool RES, bool GELU, bool OBF, bool LNOUT, bool AVGLN>
__global__ __launch_bounds__(256) void gemm_bf16(
    const __hip_bfloat16* __restrict__ A, const __hip_bfloat16* __restrict__ Bt,
    const float* __restrict__ bias, const float* __restrict__ Rsrc,
    const float* __restrict__ Rsrc2,
    void* __restrict__ Cdst,
    const float* __restrict__ lng, const float* __restrict__ lnb,
    __hip_bfloat16* __restrict__ lnout)
{
    __shared__ unsigned short As[64 * 128];    // 16 KB
    __shared__ unsigned short Bs[128 * 128];   // 32 KB
    int tid = threadIdx.x;
    int l = tid & 63, w = tid >> 6;
    int wr = w >> 1, wc = w & 1;
    int lr = l & 15, q = l >> 4;
    int m0 = blockIdx.y * 64;
    int n0 = blockIdx.x * 128;

    f32x4 acc[2][4];
    #pragma unroll
    for (int mt = 0; mt < 2; ++mt)
        #pragma unroll
        for (int nt = 0; nt < 4; ++nt) acc[mt][nt] = (f32x4){0.f, 0.f, 0.f, 0.f};

    for (int kt = 0; kt < K; kt += 128) {
        if (kt) __syncthreads();
        #pragma unroll
        for (int p = 0; p < 4; ++p) {
            int n = p * 256 + tid;
            int r = n >> 4;
            int c = (n & 15) ^ (r & 7);
            uint4 dv = *(const uint4*)(A + (size_t)(m0 + r) * K + kt + c * 8);
            *(uint4*)&As[n * 8] = dv;
        }
        #pragma unroll
        for (int p = 0; p < 8; ++p) {
            int n = p * 256 + tid;
            int r = n >> 4;
            int c = (n & 15) ^ (r & 7);
            uint4 dv = *(const uint4*)(Bt + (size_t)(n0 + r) * K + kt + c * 8);
            *(uint4*)&Bs[n * 8] = dv;
        }
        __syncthreads();

        #pragma unroll
        for (int kk = 0; kk < 4; ++kk) {
            bf16x8 afr[2], bfr[4];
            #pragma unroll
            for (int mt = 0; mt < 2; ++mt) {
                int rA = wr * 32 + mt * 16 + lr;
                int cc = (kk * 4 + q) ^ (rA & 7);
                afr[mt] = *(const bf16x8*)&As[(rA * 16 + cc) * 8];
            }
            #pragma unroll
            for (int nt = 0; nt < 4; ++nt) {
                int rB = wc * 64 + nt * 16 + lr;
                int cc = (kk * 4 + q) ^ (rB & 7);
                bfr[nt] = *(const bf16x8*)&Bs[(rB * 16 + cc) * 8];
            }
            #pragma unroll
            for (int mt = 0; mt < 2; ++mt)
                #pragma unroll
                for (int nt = 0; nt < 4; ++nt)
                    acc[mt][nt] = __builtin_amdgcn_mfma_f32_16x16x32_bf16(
                        afr[mt], bfr[nt], acc[mt][nt], 0, 0, 0);
        }
    }

    if (!LNOUT) {
        #pragma unroll
        for (int mt = 0; mt < 2; ++mt) {
            #pragma unroll
            for (int nt = 0; nt < 4; ++nt) {
                int col = n0 + wc * 64 + nt * 16 + lr;
                float bv = BIAS ? bias[col] : 0.f;
                #pragma unroll
                for (int r = 0; r < 4; ++r) {
                    int row = m0 + wr * 32 + mt * 16 + q * 4 + r;
                    float val = acc[mt][nt][r] + bv;
                    if (GELU) val = gelu_exact(val);
                    if (RES) val += Rsrc[(size_t)row * N + col];
                    if (OBF) ((__hip_bfloat16*)Cdst)[(size_t)row * N + col] = __float2bfloat16(val);
                    else     ((float*)Cdst)[(size_t)row * N + col] = val;
                }
            }
        }
    } else {
        float* fp = (float*)Bs;    // 64 x 128 fp32 tile = 32 KB (Bs reused)
        __syncthreads();           // all waves done reading As/Bs
        #pragma unroll
        for (int mt = 0; mt < 2; ++mt) {
            #pragma unroll
            for (int nt = 0; nt < 4; ++nt) {
                int col = wc * 64 + nt * 16 + lr;
                float bv = BIAS ? bias[col] : 0.f;
                #pragma unroll
                for (int r = 0; r < 4; ++r) {
                    int rowL = wr * 32 + mt * 16 + q * 4 + r;
                    float val = acc[mt][nt][r] + bv;
                    if (RES) val += Rsrc[(size_t)(m0 + rowL) * N + col];
                    fp[rowL * 128 + col] = val;
                }
            }
        }
        __syncthreads();
        int rl = tid >> 2, sub = tid & 3;          // 64 rows x 4 col-groups
        float s = 0.f, sq = 0.f;
        #pragma unroll
        for (int c4 = 0; c4 < 8; ++c4) {
            float4 v = *(const float4*)&fp[rl * 128 + sub * 32 + c4 * 4];
            if (AVGLN) {
                float4 xo = *(const float4*)(Rsrc2 + (size_t)(m0 + rl) * 128 + sub * 32 + c4 * 4);
                v.x = (v.x + xo.x) * 0.5f; v.y = (v.y + xo.y) * 0.5f;
                v.z = (v.z + xo.z) * 0.5f; v.w = (v.w + xo.w) * 0.5f;
            }
            s  += (v.x + v.y) + (v.z + v.w);
            sq += (v.x * v.x + v.y * v.y) + (v.z * v.z + v.w * v.w);
        }
        s  += __shfl_xor(s, 1);  s  += __shfl_xor(s, 2);
        sq += __shfl_xor(sq, 1); sq += __shfl_xor(sq, 2);
        float mean = s * (1.0f / 128.0f);
        float var  = sq * (1.0f / 128.0f) - mean * mean;
        float rstd = rsqrtf(var + 1e-5f);
        int rowG = m0 + rl;
        #pragma unroll
        for (int c4 = 0; c4 < 8; ++c4) {
            int col = sub * 32 + c4 * 4;
            float4 v  = *(const float4*)&fp[rl * 128 + col];
            if (AVGLN) {
                float4 xo = *(const float4*)(Rsrc2 + (size_t)rowG * 128 + col);
                v.x = (v.x + xo.x) * 0.5f; v.y = (v.y + xo.y) * 0.5f;
                v.z = (v.z + xo.z) * 0.5f; v.w = (v.w + xo.w) * 0.5f;
            } else {
                *(float4*)((float*)Cdst + (size_t)rowG * 128 + col) = v;   // residual stream
            }
            float4 g4 = *(const float4*)(lng + col);
            float4 b4 = *(const float4*)(lnb + col);
            unsigned short pk[4];
            pk[0] = f2bs((v.x - mean) * rstd * g4.x + b4.x);
            pk[1] = f2bs((v.y - mean) * rstd * g4.y + b4.y);
            pk[2] = f2bs((v.z - mean) * rstd * g4.z + b4.z);
            pk[3] = f2bs((v.w - mean) * rstd * g4.w + b4.w);
            *(ushort4*)((unsigned short*)lnout + (size_t)rowG * 128 + col) = *(ushort4*)&pk[0];
        }
    }
}

// ---------------- attention: MFMA flash-style, paired j-tiles ----------------
// Two 16-col S tiles fill a 16x32 P tile; one PV-MFMA + one l-MFMA consume full K=32.
// Odd tile counts use a virtual tile s+1 whose P entries are forced to 0 by the
// causal mask (its knb rows are real, in-bounds data -> finite).
__global__ __launch_bounds__(256) void attn_kernel(
    const __hip_bfloat16* __restrict__ qkv, __hip_bfloat16* __restrict__ o)
{
    int z  = blockIdx.x >> 9;
    int bh = blockIdx.x & 511;
    int b = bh >> 3, hh = bh & 7;
    const unsigned short* base = (const unsigned short*)qkv + (size_t)b * LL * 256 + hh * DHH;

    __shared__ unsigned short knb[LL + 2][24];   // qhat/khat bf16; cols 16..23 zeroed
    __shared__ unsigned short vtb[16][LL + 24];  // V^T bf16; cols 384..407 zeroed
    __shared__ float cq[LL];                     // 0.25*|q|
    __shared__ unsigned short ptile[4][16][40];  // per-wave 16x32 P tile (+pad)

    int t = threadIdx.x;
    for (int r = t; r < LL; r += 256) {
        const unsigned short* qp = base + (size_t)r * 256;
        unsigned short qs[16], vs16[16];
        *(uint4*)&qs[0]  = *(const uint4*)(qp);
        *(uint4*)&qs[8]  = *(const uint4*)(qp + 8);
        *(uint4*)&vs16[0] = *(const uint4*)(qp + 128);
        *(uint4*)&vs16[8] = *(const uint4*)(qp + 136);
        float q[16];
        #pragma unroll
        for (int d = 0; d < 16; ++d) q[d] = bs2f(qs[d]);
        float nrm = 0.f;
        #pragma unroll
        for (int d = 0; d < 16; ++d) nrm = fmaf(q[d], q[d], nrm);
        float qn = sqrtf(nrm);
        float inv = 1.0f / fmaxf(qn, 1e-12f);
        cq[r] = 0.25f * qn;
        unsigned short kb[16];
        #pragma unroll
        for (int d = 0; d < 16; ++d) kb[d] = f2bs(q[d] * inv);
        *(uint4*)&knb[r][0] = *(uint4*)&kb[0];
        *(uint4*)&knb[r][8] = *(uint4*)&kb[8];
        *(uint4*)&knb[r][16] = make_uint4(0u, 0u, 0u, 0u);
        #pragma unroll
        for (int d = 0; d < 16; ++d) vtb[d][r] = vs16[d];
    }
    if (t < 16) {
        #pragma unroll
        for (int c = 0; c < 24; ++c) vtb[t][LL + c] = 0;
    }

    int w = t >> 6, l = t & 63;
    int lr = l & 15, q4 = l >> 4;
    *(uint2*)&ptile[w][lr][16 + q4 * 4] = make_uint2(0u, 0u);
    __syncthreads();

    bf16x8 zfrag = {0, 0, 0, 0, 0, 0, 0, 0};
    bf16x8 onesf;
    #pragma unroll
    for (int i = 0; i < 8; ++i) onesf[i] = (short)0x3F80;

    int slot = 2 * w + z;
    int strips[3] = { slot, 15 - slot, 16 + slot };
    #pragma unroll
    for (int si = 0; si < 3; ++si) {
        int s = strips[si];
        int r0 = s * 16;
        bf16x8 afrag = *(const bf16x8*)&knb[r0 + lr][(q4 & 1) * 8];
        afrag = (q4 < 2) ? afrag : zfrag;
        float ccv[4];
        #pragma unroll
        for (int reg = 0; reg < 4; ++reg) ccv[reg] = cq[r0 + q4 * 4 + reg];

        f32x4 oacc = (f32x4){0.f, 0.f, 0.f, 0.f};
        f32x4 lacc = (f32x4){0.f, 0.f, 0.f, 0.f};

        for (int jt = 0; jt <= s; jt += 2) {
            // pair (jt, jt+1); jt+1 may be the virtual tile (masked to zero).
            bf16x8 bf0 = *(const bf16x8*)&knb[jt * 16 + lr][q4 * 8];
            f32x4 s0 = __builtin_amdgcn_mfma_f32_16x16x32_bf16(
                afrag, bf0, (f32x4){0.f, 0.f, 0.f, 0.f}, 0, 0, 0);
            bf16x8 bf1 = *(const bf16x8*)&knb[(jt + 1) * 16 + lr][q4 * 8];
            f32x4 s1 = __builtin_amdgcn_mfma_f32_16x16x32_bf16(
                afrag, bf1, (f32x4){0.f, 0.f, 0.f, 0.f}, 0, 0, 0);
            int colg0 = jt * 16 + lr;
            #pragma unroll
            for (int reg = 0; reg < 4; ++reg) {
                int rowg = r0 + q4 * 4 + reg;
                float p0 = __expf(fmaf(s0[reg], ccv[reg], -ccv[reg]));
                p0 = (colg0 < rowg) ? p0 : 0.f;
                float p1 = __expf(fmaf(s1[reg], ccv[reg], -ccv[reg]));
                p1 = (colg0 + 16 < rowg) ? p1 : 0.f;
                ptile[w][q4 * 4 + reg][lr] = f2bs(p0);
                ptile[w][q4 * 4 + reg][16 + lr] = f2bs(p1);
            }
            asm volatile("s_waitcnt lgkmcnt(0)" ::: "memory");
            bf16x8 pfrag = *(const bf16x8*)&ptile[w][lr][q4 * 8];
            bf16x8 vfrag = *(const bf16x8*)&vtb[lr][jt * 16 + q4 * 8];
            oacc = __builtin_amdgcn_mfma_f32_16x16x32_bf16(pfrag, vfrag, oacc, 0, 0, 0);
            lacc = __builtin_amdgcn_mfma_f32_16x16x32_bf16(pfrag, onesf, lacc, 0, 0, 0);
        }

        if (s == 0 && q4 == 0) {
            lacc[0] = 1.0f;
            oacc[0] = bs2f(vtb[lr][0]);
        }
        unsigned short* ob = (unsigned short*)o + (size_t)(b * LL + r0) * DD + hh * 16 + lr;
        #pragma unroll
        for (int reg = 0; reg < 4; ++reg) {
            float ov = oacc[reg] / lacc[reg];
            ob[(size_t)(q4 * 4 + reg) * DD] = f2bs(ov);
        }
    }
}

// ---------------- final projection: MFMA split-K + reduce ----------------
__global__ __launch_bounds__(256) void final_mfma_kernel(
    const __hip_bfloat16* __restrict__ A, const __hip_bfloat16* __restrict__ Bt,
    float* __restrict__ partials)
{
    __shared__ unsigned short As[64 * 128];
    __shared__ unsigned short Bs[128 * 128];
    int tid = threadIdx.x;
    int l = tid & 63, w = tid >> 6;
    int wr = w >> 1, wc = w & 1;
    int lr = l & 15, q = l >> 4;
    int kbase = blockIdx.x * KCHUNK;

    f32x4 acc[2][4];
    #pragma unroll
    for (int mt = 0; mt < 2; ++mt)
        #pragma unroll
        for (int nt = 0; nt < 4; ++nt) acc[mt][nt] = (f32x4){0.f, 0.f, 0.f, 0.f};

    for (int kt = 0; kt < KCHUNK; kt += 128) {
        if (kt) __syncthreads();
        #pragma unroll
        for (int p = 0; p < 4; ++p) {
            int n = p * 256 + tid;
            int r = n >> 4;
            int c = (n & 15) ^ (r & 7);
            uint4 dv = *(const uint4*)(A + (size_t)r * KP + kbase + kt + c * 8);
            *(uint4*)&As[n * 8] = dv;
        }
        #pragma unroll
        for (int p = 0; p < 8; ++p) {
            int n = p * 256 + tid;
            int r = n >> 4;
            int c = (n & 15) ^ (r & 7);
            uint4 dv = *(const uint4*)(Bt + (size_t)r * KP + kbase + kt + c * 8);
            *(uint4*)&Bs[n * 8] = dv;
        }
        __syncthreads();

        #pragma unroll
        for (int kk = 0; kk < 4; ++kk) {
            bf16x8 afr[2], bfr[4];
            #pragma unroll
            for (int mt = 0; mt < 2; ++mt) {
                int rA = wr * 32 + mt * 16 + lr;
                int cc = (kk * 4 + q) ^ (rA & 7);
                afr[mt] = *(const bf16x8*)&As[(rA * 16 + cc) * 8];
            }
            #pragma unroll
            for (int nt = 0; nt < 4; ++nt) {
                int rB = wc * 64 + nt * 16 + lr;
                int cc = (kk * 4 + q) ^ (rB & 7);
                bfr[nt] = *(const bf16x8*)&Bs[(rB * 16 + cc) * 8];
            }
            #pragma unroll
            for (int mt = 0; mt < 2; ++mt)
                #pragma unroll
                for (int nt = 0; nt < 4; ++nt)
                    acc[mt][nt] = __builtin_amdgcn_mfma_f32_16x16x32_bf16(
                        afr[mt], bfr[nt], acc[mt][nt], 0, 0, 0);
        }
    }

    float* dst = partials + (size_t)blockIdx.x * (64 * 128);
    #pragma unroll
    for (int mt = 0; mt < 2; ++mt) {
        #pragma unroll
        for (int nt = 0; nt < 4; ++nt) {
            int col = wc * 64 + nt * 16 + lr;
            #pragma unroll
            for (int r = 0; r < 4; ++r) {
                int row = wr * 32 + mt * 16 + q * 4 + r;
                dst[row * 128 + col] = acc[mt][nt][r];
            }
        }
    }
}

__global__ __launch_bounds__(256) void final_reduce_kernel(
    const float* __restrict__ partials, const float* __restrict__ bp,
    float* __restrict__ out)
{
    int j = blockIdx.x * 256 + threadIdx.x;   // 0..8191
    float s = bp[j & (COUT - 1)];
    #pragma unroll 8
    for (int p = 0; p < KSPLIT; ++p)
        s += partials[(size_t)p * 8192 + j];
    out[j] = s;
}

// ---------------- launch ----------------
extern "C" void kernel_launch(void* const* d_in, const int* in_sizes, int n_in,
                              void* d_out, int out_size, void* d_ws, size_t ws_size,
                              hipStream_t stream)
{
    const int*   x_enc = (const int*)  d_in[0];
    const float* emb   = (const float*)d_in[1];
    const float* pos1  = (const float*)d_in[2];
    const float* pos2  = (const float*)d_in[3];
    const float* ln1_g = (const float*)d_in[4];
    const float* ln1_b = (const float*)d_in[5];
    const float* Wqk   = (const float*)d_in[6];
    const float* Wv    = (const float*)d_in[7];
    const float* Wo    = (const float*)d_in[8];
    const float* bo    = (const float*)d_in[9];
    const float* ln2_g = (const float*)d_in[10];
    const float* ln2_b = (const float*)d_in[11];
    const float* W1    = (const float*)d_in[12];
    const float* b1    = (const float*)d_in[13];
    const float* W2    = (const float*)d_in[14];
    const float* b2    = (const float*)d_in[15];
    const float* lnf_g = (const float*)d_in[16];
    const float* lnf_b = (const float*)d_in[17];
    const float* Wp    = (const float*)d_in[18];
    const float* bp    = (const float*)d_in[19];
    float* out = (float*)d_out;

    // workspace layout; SZ = 3,145,728 elements
    const size_t SZ = (size_t)MROWS * DD;
    float* ws_f = (float*)d_ws;
    float* x1 = ws_f;                    // fp32 [M,128]
    float* x2 = ws_f + SZ;               // fp32 [M,128]
    float* R  = ws_f + 2 * SZ;           // 2*SZ floats shared region
    __hip_bfloat16* qkv_bf = (__hip_bfloat16*)R;   // bf16 [M,256] (lifetime: qkv-gemm..attn)
    __hip_bfloat16* hff = (__hip_bfloat16*)R;      // bf16 [M,512] (lifetime: ff1..ff2)
    __hip_bfloat16* h_bf = (__hip_bfloat16*)(ws_f + 4 * SZ);  // bf16 [M,128]
    __hip_bfloat16* o_bf = h_bf + SZ;                          // bf16 [M,128]
    __hip_bfloat16* wqvT = o_bf + SZ;    // 6 * [256,128]
    __hip_bfloat16* woT  = wqvT + 6 * 32768;         // 6 * [128,128]
    __hip_bfloat16* w1T  = woT  + 6 * 16384;         // 6 * [512,128]
    __hip_bfloat16* w2T  = w1T  + 6 * 65536;         // 6 * [128,512]
    __hip_bfloat16* WpT  = w2T  + 6 * 65536;         // [128, 49152] bf16
    float* partials = (float*)(WpT + (size_t)COUT * KP);   // [96][8192] fp32

    castT3_kernel<<<dim3(4, 4, 18), dim3(256), 0, stream>>>(
        Wqk, Wv, Wo, wqvT, wqvT + 16384, woT);
    castT_kernel<<<dim3(4, 16, 6), dim3(256), 0, stream>>>(W1, w1T, 128, 512, 65536, 65536);
    castT_kernel<<<dim3(16, 4, 6), dim3(256), 0, stream>>>(W2, w2T, 512, 128, 65536, 65536);
    castT_kernel<<<dim3(KP / 32, 4, 1), dim3(256), 0, stream>>>(Wp, WpT, KP, 128, 0, 0);

    embed_kernel<<<dim3(MROWS * 32 / 256), dim3(256), 0, stream>>>(x_enc, emb, pos1, pos2, x1, x2);
    // layer-0 ln1 (subsequent ln1/ln2 are fused into ff2/wo epilogues)
    ln_kernel<<<dim3(MROWS / 4), dim3(256), 0, stream>>>(x2, ln1_g, ln1_b, h_bf);

    for (int d = 0; d < DEPTH; ++d) {
        const float* bod = bo + d * DD;
        const float* l2g = ln2_g + d * DD;
        const float* l2b = ln2_b + d * DD;
        const float* b1d = b1 + d * FFD;
        const float* b2d = b2 + d * DD;
        const __hip_bfloat16* wqv_d = wqvT + (size_t)d * 32768;
        const __hip_bfloat16* wo_d  = woT  + (size_t)d * 16384;
        const __hip_bfloat16* w1_d  = w1T  + (size_t)d * 65536;
        const __hip_bfloat16* w2_d  = w2T  + (size_t)d * 65536;

        gemm_bf16<128, 256, false, false, false, true, false, false>
            <<<dim3(2, MROWS / 64), dim3(256), 0, stream>>>(
                h_bf, wqv_d, nullptr, nullptr, nullptr, qkv_bf, nullptr, nullptr, nullptr);
        attn_kernel<<<dim3(BB * HH * 2), dim3(256), 0, stream>>>(qkv_bf, o_bf);
        // x1 += o@Wo + bo ; h_bf = LN2(x1)   (fused)
        gemm_bf16<128, 128, true, true, false, false, true, false>
            <<<dim3(1, MROWS / 64), dim3(256), 0, stream>>>(
                o_bf, wo_d, bod, x1, nullptr, x1, l2g, l2b, h_bf);
        gemm_bf16<128, 512, true, false, true, true, false, false>
            <<<dim3(4, MROWS / 64), dim3(256), 0, stream>>>(
                h_bf, w1_d, b1d, nullptr, nullptr, hff, nullptr, nullptr, nullptr);
        if (d < DEPTH - 1) {
            // x2 += hff@W2 + b2 ; h_bf = LN1[d+1](x2)   (fused)
            gemm_bf16<512, 128, true, true, false, false, true, false>
                <<<dim3(1, MROWS / 64), dim3(256), 0, stream>>>(
                    hff, w2_d, b2d, x2, nullptr, x2,
                    ln1_g + (d + 1) * DD, ln1_b + (d + 1) * DD, h_bf);
        } else {
            // last layer: h_bf = LN_f((x1 + (x2 + hff@W2 + b2)) * 0.5)  (fused avg-LN)
            gemm_bf16<512, 128, true, true, false, false, true, true>
                <<<dim3(1, MROWS / 64), dim3(256), 0, stream>>>(
                    hff, w2_d, b2d, x2, x1, nullptr, lnf_g, lnf_b, h_bf);
        }
    }

    final_mfma_kernel<<<dim3(KSPLIT), dim3(256), 0, stream>>>(h_bf, WpT, partials);
    final_reduce_kernel<<<dim3(32), dim3(256), 0, stream>>>(partials, bp, out);
}